// Round 1
// 453.893 us; speedup vs baseline: 1.2895x; 1.2895x over previous
//
#include <hip/hip_runtime.h>
#include <hip/hip_bf16.h>

typedef __hip_bfloat16 bf16;
typedef __attribute__((ext_vector_type(8))) short short8;
typedef __attribute__((ext_vector_type(4))) float floatx4;

__device__ __forceinline__ float b2f(bf16 v) { return __bfloat162float(v); }
__device__ __forceinline__ float us2f(unsigned short u) {
    return __uint_as_float(((unsigned)u) << 16);
}
__device__ __forceinline__ unsigned short f2us(float f) {
    bf16 h = __float2bfloat16(f);
    return *(unsigned short*)&h;
}
__device__ __forceinline__ float lo2f(unsigned hv) { return __uint_as_float(hv << 16); }
__device__ __forceinline__ float hi2f(unsigned hv) { return __uint_as_float(hv & 0xffff0000u); }
__device__ __forceinline__ float leaky(float v) { return v > 0.f ? v : 0.2f * v; }

// flag-aware raw-input read by ELEMENT index: flag==1 -> f32 storage, else bf16
__device__ __forceinline__ float ldw(const void* p, size_t i, int f32) {
    return f32 ? ((const float*)p)[i] : b2f(((const bf16*)p)[i]);
}

// ---------------- dtype detection ----------------
__global__ void k_detect(const void* x, int* flag) {
    int i = blockIdx.x * blockDim.x + threadIdx.x;
    float v = b2f(((const bf16*)x)[i]);
    if (!(fabsf(v) < 1e10f)) atomicOr(flag, 1);  // NaN/inf/huge -> f32 storage
}

// ---------------- fused prep: x->bf16, W transpose->bf16, small weights, node0 ----
__global__ void k_prep_fused(const void* __restrict__ x, unsigned short* __restrict__ Ab,
                             int nx128,
                             const void* __restrict__ gw, unsigned short* __restrict__ Wt,
                             const void* as_, const void* ad_, const void* b_,
                             float* asF, float* adF, float* bF,
                             const int* __restrict__ batch, int* __restrict__ node0, int N,
                             const int* __restrict__ flag, int nbx, int nbN) {
    int b = blockIdx.x;
    int t = threadIdx.x;
    int f32 = *flag;
    if (b < nbx) {
        int i = b * 256 + t;
        if (i < nx128) Ab[i] = f2us(ldw(x, i, f32));
    } else if (b < nbx + 192) {
        int i = (b - nbx) * 256 + t;  // exactly 3*16384
        int l = i >> 14, rem = i & 16383, n = rem >> 7, k = rem & 127;
        Wt[i] = f2us(ldw(gw, (size_t)l * 16384 + (size_t)k * 128 + n, f32));
    } else if (b < nbx + 194) {
        int i = (b - nbx - 192) * 256 + t;
        if (i < 384) {
            asF[i] = ldw(as_, i, f32);
            adF[i] = ldw(ad_, i, f32);
            bF[i] = ldw(b_, i, f32);
        }
    } else {
        int i = (b - nbx - 194) * 256 + t;
        if (i < N) {
            int bb = batch[i];
            if (i == 0 || batch[i - 1] != bb) node0[bb] = i;
        }
    }
}

// ---------------- graph build ----------------
__global__ void k_hist(const int* __restrict__ ei, int* __restrict__ counts,
                       int* __restrict__ rank, int E) {
    int e = blockIdx.x * blockDim.x + threadIdx.x;
    if (e < E) rank[e] = atomicAdd(&counts[ei[E + e]], 1);
}

__global__ void k_scan1(const int* __restrict__ counts, int* __restrict__ offs,
                        int* __restrict__ bsums, int n) {
    __shared__ int s[256];
    int tid = threadIdx.x;
    int i = blockIdx.x * 256 + tid;
    int v = (i < n) ? counts[i] : 0;
    s[tid] = v;
    __syncthreads();
    for (int d = 1; d < 256; d <<= 1) {
        int t = (tid >= d) ? s[tid - d] : 0;
        __syncthreads();
        s[tid] += t;
        __syncthreads();
    }
    int incl = s[tid];
    if (i < n) offs[i] = incl - v;
    if (tid == 255) bsums[blockIdx.x] = incl;
}

__global__ void k_scan2(int* __restrict__ bsums, int nb) {
    __shared__ int s[512];
    int tid = threadIdx.x;
    int v = (tid < nb) ? bsums[tid] : 0;
    s[tid] = v;
    __syncthreads();
    for (int d = 1; d < 512; d <<= 1) {
        int t = (tid >= d) ? s[tid - d] : 0;
        __syncthreads();
        s[tid] += t;
        __syncthreads();
    }
    bsums[tid] = s[tid] - v;
}

__global__ void k_scan3(int* __restrict__ offs, const int* __restrict__ bsums, int n) {
    int i = blockIdx.x * 256 + threadIdx.x;
    if (i < n) offs[i] += bsums[blockIdx.x];
}

// XCD-partitioned scatter (see prior session: kills cross-XCD partial-line
// write amplification on adj).
__global__ void k_scatter8(const int* __restrict__ ei, const int* __restrict__ offs,
                           const int* __restrict__ rank, int* __restrict__ adj,
                           int E, int N) {
    int xcd = blockIdx.x & 7;
    int e = (blockIdx.x >> 3) * 256 + threadIdx.x;
    if (e >= E) return;
    int d = ei[E + e];
    int lo = (int)(((long long)N * xcd) >> 3);
    int hi = (int)(((long long)N * (xcd + 1)) >> 3);
    if (d >= lo && d < hi) adj[offs[d] + rank[e]] = ei[e];
}

// ---------------- frontier marks (output pruning) ----------------
// Only h[node0] is consumed downstream.  flag2 = node0 + their in-edge srcs
// (rows where layer-2 projection/attention scalars are needed = nodes where
// agg(l=1) must run).  flag1 = flag2 + their in-edge srcs (rows where layer-1
// projection is needed = nodes where agg(l=0) must run).
__global__ void k_mark2(const int* __restrict__ node0, const int* __restrict__ offs,
                        const int* __restrict__ counts, const int* __restrict__ adj,
                        unsigned char* __restrict__ flag2) {
    int g = blockIdx.x;  // 256 graphs
    int n0 = node0[g];
    if (threadIdx.x == 0) flag2[n0] = 1;
    int o = offs[n0], c = counts[n0];
    for (int i = threadIdx.x; i < c; i += blockDim.x) flag2[adj[o + i]] = 1;
}

__global__ void k_mark1(const unsigned char* __restrict__ flag2, const int* __restrict__ offs,
                        const int* __restrict__ counts, const int* __restrict__ adj,
                        unsigned char* __restrict__ flag1, int N) {
    int n = blockIdx.x * blockDim.x + threadIdx.x;
    if (n >= N) return;
    if (!flag2[n]) return;
    flag1[n] = 1;
    int o = offs[n], c = counts[n];
    for (int i = 0; i < c; i++) flag1[adj[o + i]] = 1;
}

// ---------------- MFMA GEMM + fused attention scalars ----------------
// rflag (optional): only rows with rflag set are loaded/computed/stored.
__global__ __launch_bounds__(256) void k_gemm_mfma(
    const unsigned short* __restrict__ Ab, const unsigned short* __restrict__ Wt,
    unsigned short* __restrict__ Bb, float4* __restrict__ asadv,
    const float* __restrict__ asF, const float* __restrict__ adF, int N,
    const unsigned char* __restrict__ rflag) {
    __shared__ unsigned short Cs[64 * 136];

    int t = threadIdx.x;
    int r0 = blockIdx.x * 64;

    int lane = t & 63;
    int w = t >> 6;
    int ln = lane & 15;
    int quad = lane >> 4;

    int arow = r0 + w * 16 + ln;
    bool valid = (arow < N) && (!rflag || rflag[arow]);
    bool wave_active = __any((int)valid);

    if (wave_active) {
        const unsigned short* ap = Ab + (size_t)arow * 128 + quad * 8;

        short8 afrag[4];
        if (valid) {
#pragma unroll
            for (int kt = 0; kt < 4; kt++)
                afrag[kt] = *(const short8*)(ap + kt * 32);
        } else {
#pragma unroll
            for (int kt = 0; kt < 4; kt++)
                afrag[kt] = (short8){0, 0, 0, 0, 0, 0, 0, 0};
        }

        floatx4 acc[8];
#pragma unroll
        for (int nt = 0; nt < 8; nt++) acc[nt] = (floatx4){0.f, 0.f, 0.f, 0.f};

#pragma unroll
        for (int nt = 0; nt < 8; nt++) {
            const unsigned short* wp = Wt + (size_t)(nt * 16 + ln) * 128 + quad * 8;
#pragma unroll
            for (int kt = 0; kt < 4; kt++) {
                short8 bfrag = *(const short8*)(wp + kt * 32);
                acc[nt] = __builtin_amdgcn_mfma_f32_16x16x32_bf16(afrag[kt], bfrag, acc[nt], 0, 0, 0);
            }
        }

        float as0[4] = {0, 0, 0, 0}, as1[4] = {0, 0, 0, 0};
        float ad0[4] = {0, 0, 0, 0}, ad1[4] = {0, 0, 0, 0};
#pragma unroll
        for (int nt = 0; nt < 8; nt++) {
            float asc = asF[nt * 16 + ln];
            float adc = adF[nt * 16 + ln];
#pragma unroll
            for (int r = 0; r < 4; r++) {
                float v = acc[nt][r];
                Cs[(w * 16 + quad * 4 + r) * 136 + nt * 16 + ln] = f2us(v);
                if (nt < 4) { as0[r] += v * asc; ad0[r] += v * adc; }
                else        { as1[r] += v * asc; ad1[r] += v * adc; }
            }
        }
#pragma unroll
        for (int mask = 1; mask <= 8; mask <<= 1) {
#pragma unroll
            for (int r = 0; r < 4; r++) {
                as0[r] += __shfl_xor(as0[r], mask);
                as1[r] += __shfl_xor(as1[r], mask);
                ad0[r] += __shfl_xor(ad0[r], mask);
                ad1[r] += __shfl_xor(ad1[r], mask);
            }
        }
        if (ln == 0) {
#pragma unroll
            for (int r = 0; r < 4; r++) {
                int row = r0 + w * 16 + quad * 4 + r;
                if (row < N && (!rflag || rflag[row]))
                    asadv[row] = make_float4(as0[r], as1[r], ad0[r], ad1[r]);
            }
        }
    }
    __syncthreads();

    {
        int row = t >> 2;
        int grow = r0 + row;
        int cseg = (t & 3) * 32;
        if (grow < N && (!rflag || rflag[grow])) {
            const short8* srcp = (const short8*)&Cs[row * 136 + cseg];
            short8* dstp = (short8*)&Bb[(size_t)grow * 128 + cseg];
#pragma unroll
            for (int u = 0; u < 4; u++) dstp[u] = srcp[u];
        }
    }
}

// ---------------- GAT aggregation: TWO nodes per wave, depth-4 pipeline ----------------
// nodelist (optional): process nodes nodelist[0..n).  nflag (optional): skip
// nodes with nflag==0 (their output rows are never consumed downstream).
__global__ void k_gat_agg(const uint2* __restrict__ Bu2, const float4* __restrict__ asadv,
                          const int* __restrict__ offs, const int* __restrict__ counts,
                          const int* __restrict__ adj, const float* __restrict__ biasF,
                          uint2* __restrict__ Au2, float2* __restrict__ pE,
                          int n, int dorelu,
                          const int* __restrict__ nodelist,
                          const unsigned char* __restrict__ nflag) {
    int wave = (blockIdx.x * blockDim.x + threadIdx.x) >> 6;
    int lane = threadIdx.x & 63;
    int hl = lane & 31;          // lane within node-half
    int hb = lane & 32;          // shfl broadcast base for this half
    int idx = wave * 2 + (lane >> 5);
    if (idx >= n) return;
    int node = nodelist ? nodelist[idx] : idx;
    if (nflag && !nflag[node]) return;  // pruned row: half-wave exits (shfls stay in-half)
    int head = hl >> 4;          // channels 4hl..4hl+3

    float4 self = asadv[node];
    float ad0 = self.z, ad1 = self.w;
    float es0 = __expf(leaky(self.x + ad0));
    float es1 = __expf(leaky(self.y + ad1));

    int o = offs[node], c = counts[node];
    uint2 hvs = Bu2[(size_t)node * 32 + hl];
    float acc0, acc1, acc2, acc3;

    if (c <= 32) {
        // ---- fast path ----
        int src_r = 0;
        float p0 = 0.f, p1 = 0.f;
        if (hl < c) {
            src_r = adj[o + hl];
            float4 av = asadv[src_r];
            p0 = __expf(leaky(av.x + ad0));
            p1 = __expf(leaky(av.y + ad1));
        }
        float t0 = p0, t1 = p1;
#pragma unroll
        for (int mask = 1; mask <= 16; mask <<= 1) {
            t0 += __shfl_xor(t0, mask);
            t1 += __shfl_xor(t1, mask);
        }
        float inv0 = 1.f / (es0 + t0 + 1e-16f);
        float inv1 = 1.f / (es1 + t1 + 1e-16f);
        p0 *= inv0;                       // pre-scaled alphas
        p1 *= inv1;
        float aself = head ? es1 * inv1 : es0 * inv0;
        acc0 = aself * lo2f(hvs.x);
        acc1 = aself * hi2f(hvs.x);
        acc2 = aself * lo2f(hvs.y);
        acc3 = aself * hi2f(hvs.y);

        // prologue: prefetch rows for edges 0..3
        uint2 hq[4];
#pragma unroll
        for (int j = 0; j < 4; j++) {
            int s2 = __shfl(src_r, hb + j);
            hq[j] = make_uint2(0u, 0u);
            if (j < c) hq[j] = Bu2[(size_t)s2 * 32 + hl];
        }

        for (int base = 0; base < c; base += 4) {
            uint2 cur[4];
            float av4[4];
#pragma unroll
            for (int j = 0; j < 4; j++) {
                cur[j] = hq[j];
                int idx2 = (base + j) & 31;
                float a0 = __shfl(p0, hb + idx2);   // both heads broadcast;
                float a1 = __shfl(p1, hb + idx2);   // consumer selects its head
                float a = head ? a1 : a0;
                av4[j] = (base + j < c) ? a : 0.f;  // tail guard (stale cur is finite)
            }
            // issue next 4 loads before consuming cur
#pragma unroll
            for (int j = 0; j < 4; j++) {
                int nx = base + 4 + j;
                int s2 = __shfl(src_r, hb + (nx & 31));
                if (nx < c) hq[j] = Bu2[(size_t)s2 * 32 + hl];
            }
#pragma unroll
            for (int j = 0; j < 4; j++) {
                acc0 += av4[j] * lo2f(cur[j].x);
                acc1 += av4[j] * hi2f(cur[j].x);
                acc2 += av4[j] * lo2f(cur[j].y);
                acc3 += av4[j] * hi2f(cur[j].y);
            }
        }
    } else {
        // ---- slow path (rare, c>32): alphas staged in global scratch ----
        float sum0 = es0, sum1 = es1;
        for (int base = 0; base < c; base += 32) {
            int i = base + hl;
            float p0 = 0.f, p1 = 0.f;
            if (i < c) {
                int s = adj[o + i];
                float4 av = asadv[s];
                p0 = __expf(leaky(av.x + ad0));
                p1 = __expf(leaky(av.y + ad1));
                pE[o + i] = make_float2(p0, p1);
            }
            float t0 = p0, t1 = p1;
#pragma unroll
            for (int mask = 1; mask <= 16; mask <<= 1) {
                t0 += __shfl_xor(t0, mask);
                t1 += __shfl_xor(t1, mask);
            }
            sum0 += t0; sum1 += t1;
        }
        float inv0 = 1.f / (sum0 + 1e-16f);
        float inv1 = 1.f / (sum1 + 1e-16f);
        float aself = head ? es1 * inv1 : es0 * inv0;
        float invh = head ? inv1 : inv0;
        acc0 = aself * lo2f(hvs.x);
        acc1 = aself * hi2f(hvs.x);
        acc2 = aself * lo2f(hvs.y);
        acc3 = aself * hi2f(hvs.y);
        for (int i = 0; i < c; i++) {
            int s = adj[o + i];
            float2 pp = pE[o + i];
            uint2 hv = Bu2[(size_t)s * 32 + hl];
            float a = (head ? pp.y : pp.x) * invh;
            acc0 += a * lo2f(hv.x);
            acc1 += a * hi2f(hv.x);
            acc2 += a * lo2f(hv.y);
            acc3 += a * hi2f(hv.y);
        }
    }

    // lane hl covers dwords 2hl,2hl+1 of the row = channels 4hl..4hl+3
    float4 bb4 = ((const float4*)biasF)[hl];
    float q0 = acc0 + bb4.x;
    float q1 = acc1 + bb4.y;
    float q2 = acc2 + bb4.z;
    float q3 = acc3 + bb4.w;
    if (dorelu) {
        q0 = fmaxf(q0, 0.f); q1 = fmaxf(q1, 0.f);
        q2 = fmaxf(q2, 0.f); q3 = fmaxf(q3, 0.f);
    }
    Au2[(size_t)node * 32 + hl] =
        make_uint2(((unsigned)f2us(q1) << 16) | f2us(q0),
                   ((unsigned)f2us(q3) << 16) | f2us(q2));
}

// ---------------- heads: one block (4 waves) per graph ----------------
__global__ __launch_bounds__(256) void k_heads(
    const unsigned short* __restrict__ Ab, const void* __restrict__ x,
    const int* __restrict__ node0,
    const void* sW, const void* sb,
    const void* pW1, const void* pb1, const void* pW2, const void* pb2,
    const void* cW1, const void* cb1, const void* cW2, const void* cb2,
    const void* fW1, const void* fb1, const void* fW2, const void* fb2,
    const void* bW1, const void* bb1, const void* bW2, const void* bb2,
    const void* zW1, const void* zb1, const void* zW2, const void* zb2,
    void* __restrict__ outv, const int* __restrict__ flag) {
    int g = blockIdx.x;
    int t = threadIdx.x;
    int w = t >> 6;
    int lane = t & 63;
    int f32 = *flag;
    bf16* outb = (bf16*)outv;
    float* outf = (float*)outv;
    __shared__ float in150[152];
    __shared__ float part[4][64];
    __shared__ float zf[64];
    __shared__ float tmp[64];
    __shared__ float bin[96];

#define STORE_OUT(idx, val) do { if (f32) outf[idx] = (val); else outb[idx] = __float2bfloat16(val); } while (0)

    int n0 = node0[g];
    if (t < 128) in150[t] = us2f(Ab[(size_t)n0 * 128 + t]);
    else if (t < 150) in150[t] = ldw(x, (size_t)n0 * 128 + (t - 128), f32);
    __syncthreads();
    if (t >= 64 && t < 86) bin[t] = in150[128 + (t - 64)];

    {
        int i0 = w * 38, i1 = min(150, i0 + 38);
        float p = 0.f;
        for (int i = i0; i < i1; i++) p += in150[i] * ldw(sW, (size_t)i * 64 + lane, f32);
        part[w][lane] = p;
    }
    __syncthreads();
    if (w == 0) {
        float a = part[0][lane] + part[1][lane] + part[2][lane] + part[3][lane]
                + ldw(sb, lane, f32);
        a = fmaxf(a, 0.f);
        zf[lane] = a;
        bin[lane] = a;
    }
    __syncthreads();

    for (int k = 0; k < 3; k++) {
        {
            int i0 = w * 16;
            float p = 0.f;
            for (int i = i0; i < i0 + 16; i++)
                p += zf[i] * ldw(pW1, (size_t)k * 4096 + (size_t)i * 64 + lane, f32);
            part[w][lane] = p;
        }
        __syncthreads();
        if (w == 0) {
            float a = part[0][lane] + part[1][lane] + part[2][lane] + part[3][lane]
                    + ldw(pb1, k * 64 + lane, f32);
            tmp[lane] = fmaxf(a, 0.f);
        }
        __syncthreads();
        if (w < 3) {
            float v = tmp[lane] * ldw(pW2, (size_t)k * 192 + (size_t)lane * 3 + w, f32);
#pragma unroll
            for (int mask = 1; mask <= 32; mask <<= 1) v += __shfl_xor(v, mask);
            if (lane == 0) STORE_OUT(k * 768 + g * 3 + w, v + ldw(pb2, k * 3 + w, f32));
        }
        __syncthreads();
    }

    {
        int i0 = w * 16;
        float p = 0.f;
        for (int i = i0; i < i0 + 16; i++)
            p += zf[i] * ldw(cW1, (size_t)i * 64 + lane, f32);
        part[w][lane] = p;
    }
    __syncthreads();
    if (w == 0) {
        float a = part[0][lane] + part[1][lane] + part[2][lane] + part[3][lane]
                + ldw(cb1, lane, f32);
        tmp[lane] = fmaxf(a, 0.f);
    }
    __syncthreads();
    for (int base = 0; base < 5; base += 4) {
        int o = base + w;
        if (o < 5) {
            float v = tmp[lane] * ldw(cW2, (size_t)lane * 5 + o, f32);
#pragma unroll
            for (int mask = 1; mask <= 32; mask <<= 1) v += __shfl_xor(v, mask);
            if (lane == 0) {
                float r = v + ldw(cb2, o, f32);
                bin[86 + o] = r;
                STORE_OUT(2304 + g * 5 + o, r);
            }
        }
        __syncthreads();
    }

    for (int k = 0; k < 2; k++) {
        {
            int i0 = w * 16;
            float p = 0.f;
            for (int i = i0; i < i0 + 16; i++)
                p += zf[i] * ldw(fW1, (size_t)k * 4096 + (size_t)i * 64 + lane, f32);
            part[w][lane] = p;
        }
        __syncthreads();
        if (w == 0) {
            float a = part[0][lane] + part[1][lane] + part[2][lane] + part[3][lane]
                    + ldw(fb1, k * 64 + lane, f32);
            tmp[lane] = fmaxf(a, 0.f);
        }
        __syncthreads();
        if (w == 0) {
            float v = tmp[lane] * ldw(fW2, k * 64 + lane, f32);
#pragma unroll
            for (int mask = 1; mask <= 32; mask <<= 1) v += __shfl_xor(v, mask);
            if (lane == 0) {
                float r = v + ldw(fb2, k, f32);
                bin[91 + k] = r;
                STORE_OUT(3584 + k * 256 + g, r);
            }
        }
        __syncthreads();
    }

    {
        int i0 = w * 24, i1 = min(93, i0 + 24);
        float p = 0.f;
        for (int i = i0; i < i1; i++) p += bin[i] * ldw(bW1, (size_t)i * 64 + lane, f32);
        part[w][lane] = p;
    }
    __syncthreads();
    if (w == 0) {
        float a = part[0][lane] + part[1][lane] + part[2][lane] + part[3][lane]
                + ldw(bb1, lane, f32);
        tmp[lane] = fmaxf(a, 0.f);
    }
    __syncthreads();
    if (w == 0) {
        float v = tmp[lane] * ldw(bW2, lane, f32);
#pragma unroll
        for (int mask = 1; mask <= 32; mask <<= 1) v += __shfl_xor(v, mask);
        if (lane == 0) {
            float r = v + ldw(bb2, 0, f32);
            bin[93] = r;
            STORE_OUT(4096 + g, r);
        }
    }
    __syncthreads();

    {
        int i0 = w * 24, i1 = min(94, i0 + 24);
        float p = 0.f;
        for (int i = i0; i < i1; i++) p += bin[i] * ldw(zW1, (size_t)i * 64 + lane, f32);
        part[w][lane] = p;
    }
    __syncthreads();
    if (w == 0) {
        float a = part[0][lane] + part[1][lane] + part[2][lane] + part[3][lane]
                + ldw(zb1, lane, f32);
        tmp[lane] = fmaxf(a, 0.f);
    }
    __syncthreads();
    for (int base = 0; base < 8; base += 4) {
        int o = base + w;
        float v = tmp[lane] * ldw(zW2, (size_t)lane * 8 + o, f32);
#pragma unroll
        for (int mask = 1; mask <= 32; mask <<= 1) v += __shfl_xor(v, mask);
        if (lane == 0) STORE_OUT(4352 + g * 8 + o, v + ldw(zb2, o, f32));
    }
#undef STORE_OUT
}

// ---------------- host ----------------

extern "C" void kernel_launch(void* const* d_in, const int* in_sizes, int n_in,
                              void* d_out, int out_size, void* d_ws, size_t ws_size,
                              hipStream_t stream) {
    const void* x     = d_in[0];
    const int*  ei    = (const int*)d_in[1];
    const int*  batch = (const int*)d_in[2];

    int N = in_sizes[0] / 128;
    int E = in_sizes[1] / 2;

    char* w = (char*)d_ws;
    float4* asad = (float4*)w;              w += (size_t)N * 16;
    unsigned short* A = (unsigned short*)w; w += (size_t)N * 128 * 2;
    unsigned short* B = (unsigned short*)w; w += (size_t)N * 128 * 2;
    float2* pE = (float2*)w;                w += (size_t)E * 8;
    unsigned short* Wt = (unsigned short*)w; w += 3 * 16384 * 2;
    float* asF = (float*)w;                 w += 384 * 4;
    float* adF = (float*)w;                 w += 384 * 4;
    float* bF = (float*)w;                  w += 384 * 4;
    int* offs = (int*)w;                    w += (size_t)N * 4;
    int* rank = (int*)w;                    w += (size_t)E * 4;
    int* adj = (int*)w;                     w += (size_t)E * 4;
    int* bsums = (int*)w;                   w += 512 * 4;
    int* node0 = (int*)w;                   w += 256 * 4;
    // ---- contiguous zero-region (single memset) ----
    int* counts = (int*)w;                  w += (size_t)N * 4;
    int* flag = (int*)w;                    w += 64;
    unsigned char* flag1 = (unsigned char*)w; w += (size_t)N;
    unsigned char* flag2 = (unsigned char*)w; w += (size_t)N;

    int nb = (N + 255) / 256;
    int nbx = (N * 128 + 255) / 256;

    hipMemsetAsync(counts, 0, (size_t)N * 4 + 64 + (size_t)N * 2, stream);

    k_detect<<<16, 256, 0, stream>>>(x, flag);

    k_prep_fused<<<nbx + 194 + nb, 256, 0, stream>>>(
        x, A, N * 128, d_in[3], Wt, d_in[4], d_in[5], d_in[6],
        asF, adF, bF, batch, node0, N, flag, nbx, nb);

    k_hist<<<(E + 255) / 256, 256, 0, stream>>>(ei, counts, rank, E);
    k_scan1<<<nb, 256, 0, stream>>>(counts, offs, bsums, N);
    k_scan2<<<1, 512, 0, stream>>>(bsums, nb);
    k_scan3<<<nb, 256, 0, stream>>>(offs, bsums, N);
    k_scatter8<<<8 * ((E + 255) / 256), 256, 0, stream>>>(ei, offs, rank, adj, E, N);

    // frontier masks: flag2 = node0 + srcs(node0); flag1 = flag2 + srcs(flag2)
    k_mark2<<<256, 64, 0, stream>>>(node0, offs, counts, adj, flag2);
    k_mark1<<<nb, 256, 0, stream>>>(flag2, offs, counts, adj, flag1, N);

    // agg grid: 2 nodes per wave, 4 waves per block
    int nwaves = (N + 1) / 2;
    int aggblocks = (nwaves + 3) / 4;

    // layer 0: full gemm, agg only where layer-1 projection is needed (flag1)
    k_gemm_mfma<<<(N + 63) / 64, 256, 0, stream>>>(
        A, Wt, B, asad, asF, adF, N, (const unsigned char*)nullptr);
    k_gat_agg<<<aggblocks, 256, 0, stream>>>(
        (const uint2*)B, asad, offs, counts, adj, bF, (uint2*)A, pE, N, 1,
        (const int*)nullptr, flag1);

    // layer 1: gemm on flag1 rows, agg only where layer-2 projection is needed (flag2)
    k_gemm_mfma<<<(N + 63) / 64, 256, 0, stream>>>(
        A, Wt + 16384, B, asad, asF + 128, adF + 128, N, flag1);
    k_gat_agg<<<aggblocks, 256, 0, stream>>>(
        (const uint2*)B, asad, offs, counts, adj, bF + 128, (uint2*)A, pE, N, 1,
        (const int*)nullptr, flag2);

    // layer 2: gemm on flag2 rows, agg ONLY at the 256 node0 rows (all that
    // the heads consume)
    k_gemm_mfma<<<(N + 63) / 64, 256, 0, stream>>>(
        A, Wt + 2 * 16384, B, asad, asF + 256, adF + 256, N, flag2);
    k_gat_agg<<<32, 256, 0, stream>>>(
        (const uint2*)B, asad, offs, counts, adj, bF + 256, (uint2*)A, pE, 256, 0,
        node0, (const unsigned char*)nullptr);

    k_heads<<<256, 256, 0, stream>>>(A, x, node0,
                                     d_in[7], d_in[8], d_in[9], d_in[10], d_in[11], d_in[12],
                                     d_in[13], d_in[14], d_in[15], d_in[16],
                                     d_in[17], d_in[18], d_in[19], d_in[20],
                                     d_in[21], d_in[22], d_in[23], d_in[24],
                                     d_in[25], d_in[26], d_in[27], d_in[28],
                                     d_out, flag);
}

// Round 3
// 433.075 us; speedup vs baseline: 1.3515x; 1.0481x over previous
//
#include <hip/hip_runtime.h>
#include <hip/hip_bf16.h>

typedef __hip_bfloat16 bf16;
typedef __attribute__((ext_vector_type(8))) short short8;
typedef __attribute__((ext_vector_type(4))) float floatx4;

__device__ __forceinline__ float b2f(bf16 v) { return __bfloat162float(v); }
__device__ __forceinline__ float us2f(unsigned short u) {
    return __uint_as_float(((unsigned)u) << 16);
}
__device__ __forceinline__ unsigned short f2us(float f) {
    bf16 h = __float2bfloat16(f);
    return *(unsigned short*)&h;
}
__device__ __forceinline__ float lo2f(unsigned hv) { return __uint_as_float(hv << 16); }
__device__ __forceinline__ float hi2f(unsigned hv) { return __uint_as_float(hv & 0xffff0000u); }
__device__ __forceinline__ float leaky(float v) { return v > 0.f ? v : 0.2f * v; }

// flag-aware raw-input read by ELEMENT index: flag==1 -> f32 storage, else bf16
__device__ __forceinline__ float ldw(const void* p, size_t i, int f32) {
    return f32 ? ((const float*)p)[i] : b2f(((const bf16*)p)[i]);
}

// compile-time-dispatch variant (used by heads: storage dtype is kernel-uniform)
template <int F32>
__device__ __forceinline__ float LDWt(const void* p, size_t i) {
    return F32 ? ((const float*)p)[i] : b2f(((const bf16*)p)[i]);
}

// full-wave (64-lane) butterfly sum; every lane ends with the total
__device__ __forceinline__ float wsum64(float v) {
#pragma unroll
    for (int m = 1; m <= 32; m <<= 1) v += __shfl_xor(v, m);
    return v;
}

// ---------------- dtype detection ----------------
__global__ void k_detect(const void* x, int* flag) {
    int i = blockIdx.x * blockDim.x + threadIdx.x;
    float v = b2f(((const bf16*)x)[i]);
    if (!(fabsf(v) < 1e10f)) atomicOr(flag, 1);  // NaN/inf/huge -> f32 storage
}

// ---------------- fused prep: x->bf16, W transpose->bf16, small weights, node0 ----
__global__ void k_prep_fused(const void* __restrict__ x, unsigned short* __restrict__ Ab,
                             int nx128,
                             const void* __restrict__ gw, unsigned short* __restrict__ Wt,
                             const void* as_, const void* ad_, const void* b_,
                             float* asF, float* adF, float* bF,
                             const int* __restrict__ batch, int* __restrict__ node0, int N,
                             const int* __restrict__ flag, int nbx, int nbN) {
    int b = blockIdx.x;
    int t = threadIdx.x;
    int f32 = *flag;
    if (b < nbx) {
        int i = b * 256 + t;
        if (i < nx128) Ab[i] = f2us(ldw(x, i, f32));
    } else if (b < nbx + 192) {
        int i = (b - nbx) * 256 + t;  // exactly 3*16384
        int l = i >> 14, rem = i & 16383, n = rem >> 7, k = rem & 127;
        Wt[i] = f2us(ldw(gw, (size_t)l * 16384 + (size_t)k * 128 + n, f32));
    } else if (b < nbx + 194) {
        int i = (b - nbx - 192) * 256 + t;
        if (i < 384) {
            asF[i] = ldw(as_, i, f32);
            adF[i] = ldw(ad_, i, f32);
            bF[i] = ldw(b_, i, f32);
        }
    } else {
        int i = (b - nbx - 194) * 256 + t;
        if (i < N) {
            int bb = batch[i];
            if (i == 0 || batch[i - 1] != bb) node0[bb] = i;
        }
    }
}

// ---------------- prefix scans (block-local + block-sum pass) ----------------
// NOTE: no scan3 — consumers compute offs[n] + bsums[n>>8] on the fly.
__global__ void k_scan1(const int* __restrict__ counts, int* __restrict__ offs,
                        int* __restrict__ bsums, int n) {
    __shared__ int s[256];
    int tid = threadIdx.x;
    int i = blockIdx.x * 256 + tid;
    int v = (i < n) ? counts[i] : 0;
    s[tid] = v;
    __syncthreads();
    for (int d = 1; d < 256; d <<= 1) {
        int t = (tid >= d) ? s[tid - d] : 0;
        __syncthreads();
        s[tid] += t;
        __syncthreads();
    }
    int incl = s[tid];
    if (i < n) offs[i] = incl - v;
    if (tid == 255) bsums[blockIdx.x] = incl;
}

__global__ void k_scan2(int* __restrict__ bsums, int nb) {
    __shared__ int s[512];
    int tid = threadIdx.x;
    int v = (tid < nb) ? bsums[tid] : 0;
    s[tid] = v;
    __syncthreads();
    for (int d = 1; d < 512; d <<= 1) {
        int t = (tid >= d) ? s[tid - d] : 0;
        __syncthreads();
        s[tid] += t;
        __syncthreads();
    }
    bsums[tid] = s[tid] - v;
}

// ---------------- fused scatter + mark1 (+ flag1 self-propagate) ----------------
// scatter: XCD-partitioned (one XCD's L2 owns each adj line -> no cross-XCD
// partial-line write amplification).  mark1 role: flag1[src]=1 for edges into
// flag2 nodes; self role: flag1 |= flag2.
__global__ void k_scatter_mark(const int* __restrict__ ei, const int* __restrict__ offs,
                               const int* __restrict__ bsums, const int* __restrict__ rank,
                               int* __restrict__ adj, const unsigned char* __restrict__ flag2,
                               unsigned char* __restrict__ flag1,
                               int E, int N, int sBlocks, int mBlocks) {
    int b = blockIdx.x;
    if (b < sBlocks) {
        int xcd = b & 7;
        int e = (b >> 3) * 256 + threadIdx.x;
        if (e >= E) return;
        int d = ei[E + e];
        int lo = (int)(((long long)N * xcd) >> 3);
        int hi = (int)(((long long)N * (xcd + 1)) >> 3);
        if (d >= lo && d < hi) adj[offs[d] + bsums[d >> 8] + rank[e]] = ei[e];
    } else if (b < sBlocks + mBlocks) {
        int e = (b - sBlocks) * 256 + threadIdx.x;
        if (e < E && flag2[ei[E + e]]) flag1[ei[e]] = 1;
    } else {
        int i = (b - sBlocks - mBlocks) * 256 + threadIdx.x;
        if (i < N && flag2[i]) flag1[i] = 1;
    }
}

// ---------------- MFMA GEMM body + fused attention scalars ----------------
// rflag (optional): only rows with rflag set are loaded/computed/stored.
__device__ __forceinline__ void gemm_body(
    const unsigned short* __restrict__ Ab, const unsigned short* __restrict__ Wt,
    unsigned short* __restrict__ Bb, float4* __restrict__ asadv,
    const float* __restrict__ asF, const float* __restrict__ adF, int N,
    const unsigned char* __restrict__ rflag, int bb) {
    __shared__ unsigned short Cs[64 * 136];

    int t = threadIdx.x;
    int r0 = bb * 64;

    int lane = t & 63;
    int w = t >> 6;
    int ln = lane & 15;
    int quad = lane >> 4;

    int arow = r0 + w * 16 + ln;
    bool valid = (arow < N) && (!rflag || rflag[arow]);
    bool wave_active = __any((int)valid);

    if (wave_active) {
        const unsigned short* ap = Ab + (size_t)arow * 128 + quad * 8;

        short8 afrag[4];
        if (valid) {
#pragma unroll
            for (int kt = 0; kt < 4; kt++)
                afrag[kt] = *(const short8*)(ap + kt * 32);
        } else {
#pragma unroll
            for (int kt = 0; kt < 4; kt++)
                afrag[kt] = (short8){0, 0, 0, 0, 0, 0, 0, 0};
        }

        floatx4 acc[8];
#pragma unroll
        for (int nt = 0; nt < 8; nt++) acc[nt] = (floatx4){0.f, 0.f, 0.f, 0.f};

#pragma unroll
        for (int nt = 0; nt < 8; nt++) {
            const unsigned short* wp = Wt + (size_t)(nt * 16 + ln) * 128 + quad * 8;
#pragma unroll
            for (int kt = 0; kt < 4; kt++) {
                short8 bfrag = *(const short8*)(wp + kt * 32);
                acc[nt] = __builtin_amdgcn_mfma_f32_16x16x32_bf16(afrag[kt], bfrag, acc[nt], 0, 0, 0);
            }
        }

        float as0[4] = {0, 0, 0, 0}, as1[4] = {0, 0, 0, 0};
        float ad0[4] = {0, 0, 0, 0}, ad1[4] = {0, 0, 0, 0};
#pragma unroll
        for (int nt = 0; nt < 8; nt++) {
            float asc = asF[nt * 16 + ln];
            float adc = adF[nt * 16 + ln];
#pragma unroll
            for (int r = 0; r < 4; r++) {
                float v = acc[nt][r];
                Cs[(w * 16 + quad * 4 + r) * 136 + nt * 16 + ln] = f2us(v);
                if (nt < 4) { as0[r] += v * asc; ad0[r] += v * adc; }
                else        { as1[r] += v * asc; ad1[r] += v * adc; }
            }
        }
#pragma unroll
        for (int mask = 1; mask <= 8; mask <<= 1) {
#pragma unroll
            for (int r = 0; r < 4; r++) {
                as0[r] += __shfl_xor(as0[r], mask);
                as1[r] += __shfl_xor(as1[r], mask);
                ad0[r] += __shfl_xor(ad0[r], mask);
                ad1[r] += __shfl_xor(ad1[r], mask);
            }
        }
        if (ln == 0) {
#pragma unroll
            for (int r = 0; r < 4; r++) {
                int row = r0 + w * 16 + quad * 4 + r;
                if (row < N && (!rflag || rflag[row]))
                    asadv[row] = make_float4(as0[r], as1[r], ad0[r], ad1[r]);
            }
        }
    }
    __syncthreads();

    {
        int row = t >> 2;
        int grow = r0 + row;
        int cseg = (t & 3) * 32;
        if (grow < N && (!rflag || rflag[grow])) {
            const short8* srcp = (const short8*)&Cs[row * 136 + cseg];
            short8* dstp = (short8*)&Bb[(size_t)grow * 128 + cseg];
#pragma unroll
            for (int u = 0; u < 4; u++) dstp[u] = srcp[u];
        }
    }
}

// layers 1,2: plain GEMM with row mask
__global__ __launch_bounds__(256) void k_gemm_mfma(
    const unsigned short* __restrict__ Ab, const unsigned short* __restrict__ Wt,
    unsigned short* __restrict__ Bb, float4* __restrict__ asadv,
    const float* __restrict__ asF, const float* __restrict__ adF, int N,
    const unsigned char* __restrict__ rflag) {
    gemm_body(Ab, Wt, Bb, asadv, asF, adF, N, rflag, blockIdx.x);
}

// layer 0: GEMM fused with edge histogram (+rank) and edge-based mark2.
// Hist blocks come FIRST in the grid so the device-scope atomic write stream
// (the ~800 GB/s hist bottleneck) starts immediately and overlaps the MFMA
// work, which uses disjoint pipes.
__global__ __launch_bounds__(256) void k_gemm0_hist(
    const unsigned short* __restrict__ Ab, const unsigned short* __restrict__ Wt,
    unsigned short* __restrict__ Bb, float4* __restrict__ asadv,
    const float* __restrict__ asF, const float* __restrict__ adF, int N,
    const int* __restrict__ ei, int* __restrict__ counts, int* __restrict__ rank,
    const int* __restrict__ batch, const int* __restrict__ node0,
    unsigned char* __restrict__ flag2, int E, int histBlocks) {
    int b = blockIdx.x;
    if (b < histBlocks) {
        int e = b * 256 + threadIdx.x;
        if (e < E) {
            int d = ei[E + e];
            rank[e] = atomicAdd(&counts[d], 1);
            // mark2 (edge form): src feeds a graph-root node -> layer-2 frontier
            if (d == node0[batch[d]]) flag2[ei[e]] = 1;
        }
        return;
    }
    if (b == histBlocks) {
        if (threadIdx.x < 256) flag2[node0[threadIdx.x]] = 1;
        return;
    }
    gemm_body(Ab, Wt, Bb, asadv, asF, adF, N, nullptr, b - histBlocks - 1);
}

// ---------------- GAT aggregation: TWO nodes per wave, depth-4 pipeline ----------------
// nflag (optional): skip nodes with nflag==0 (their outputs are never consumed).
__global__ void k_gat_agg(const uint2* __restrict__ Bu2, const float4* __restrict__ asadv,
                          const int* __restrict__ offs, const int* __restrict__ bsums,
                          const int* __restrict__ counts,
                          const int* __restrict__ adj, const float* __restrict__ biasF,
                          uint2* __restrict__ Au2, float2* __restrict__ pE,
                          int n, int dorelu,
                          const unsigned char* __restrict__ nflag) {
    int wave = (blockIdx.x * blockDim.x + threadIdx.x) >> 6;
    int lane = threadIdx.x & 63;
    int hl = lane & 31;          // lane within node-half
    int hb = lane & 32;          // shfl broadcast base for this half
    int node = wave * 2 + (lane >> 5);
    if (node >= n) return;
    if (nflag && !nflag[node]) return;  // pruned row: half-wave exits (shfls stay in-half)
    int head = hl >> 4;          // channels 4hl..4hl+3

    float4 self = asadv[node];
    float ad0 = self.z, ad1 = self.w;
    float es0 = __expf(leaky(self.x + ad0));
    float es1 = __expf(leaky(self.y + ad1));

    int o = offs[node] + bsums[node >> 8];
    int c = counts[node];
    uint2 hvs = Bu2[(size_t)node * 32 + hl];
    float acc0, acc1, acc2, acc3;

    if (c <= 32) {
        // ---- fast path ----
        int src_r = 0;
        float p0 = 0.f, p1 = 0.f;
        if (hl < c) {
            src_r = adj[o + hl];
            float4 av = asadv[src_r];
            p0 = __expf(leaky(av.x + ad0));
            p1 = __expf(leaky(av.y + ad1));
        }
        float t0 = p0, t1 = p1;
#pragma unroll
        for (int mask = 1; mask <= 16; mask <<= 1) {
            t0 += __shfl_xor(t0, mask);
            t1 += __shfl_xor(t1, mask);
        }
        float inv0 = 1.f / (es0 + t0 + 1e-16f);
        float inv1 = 1.f / (es1 + t1 + 1e-16f);
        p0 *= inv0;                       // pre-scaled alphas
        p1 *= inv1;
        float aself = head ? es1 * inv1 : es0 * inv0;
        acc0 = aself * lo2f(hvs.x);
        acc1 = aself * hi2f(hvs.x);
        acc2 = aself * lo2f(hvs.y);
        acc3 = aself * hi2f(hvs.y);

        // prologue: prefetch rows for edges 0..3
        uint2 hq[4];
#pragma unroll
        for (int j = 0; j < 4; j++) {
            int s2 = __shfl(src_r, hb + j);
            hq[j] = make_uint2(0u, 0u);
            if (j < c) hq[j] = Bu2[(size_t)s2 * 32 + hl];
        }

        for (int base = 0; base < c; base += 4) {
            uint2 cur[4];
            float av4[4];
#pragma unroll
            for (int j = 0; j < 4; j++) {
                cur[j] = hq[j];
                int idx2 = (base + j) & 31;
                float a0 = __shfl(p0, hb + idx2);   // both heads broadcast (full exec);
                float a1 = __shfl(p1, hb + idx2);   // consumer selects its head
                float a = head ? a1 : a0;
                av4[j] = (base + j < c) ? a : 0.f;  // tail guard (stale cur is finite)
            }
            // issue next 4 loads before consuming cur
#pragma unroll
            for (int j = 0; j < 4; j++) {
                int nx = base + 4 + j;
                int s2 = __shfl(src_r, hb + (nx & 31));
                if (nx < c) hq[j] = Bu2[(size_t)s2 * 32 + hl];
            }
#pragma unroll
            for (int j = 0; j < 4; j++) {
                acc0 += av4[j] * lo2f(cur[j].x);
                acc1 += av4[j] * hi2f(cur[j].x);
                acc2 += av4[j] * lo2f(cur[j].y);
                acc3 += av4[j] * hi2f(cur[j].y);
            }
        }
    } else {
        // ---- slow path (rare, c>32): alphas staged in global scratch ----
        float sum0 = es0, sum1 = es1;
        for (int base = 0; base < c; base += 32) {
            int i = base + hl;
            float p0 = 0.f, p1 = 0.f;
            if (i < c) {
                int s = adj[o + i];
                float4 av = asadv[s];
                p0 = __expf(leaky(av.x + ad0));
                p1 = __expf(leaky(av.y + ad1));
                pE[o + i] = make_float2(p0, p1);
            }
            float t0 = p0, t1 = p1;
#pragma unroll
            for (int mask = 1; mask <= 16; mask <<= 1) {
                t0 += __shfl_xor(t0, mask);
                t1 += __shfl_xor(t1, mask);
            }
            sum0 += t0; sum1 += t1;
        }
        float inv0 = 1.f / (sum0 + 1e-16f);
        float inv1 = 1.f / (sum1 + 1e-16f);
        float aself = head ? es1 * inv1 : es0 * inv0;
        float invh = head ? inv1 : inv0;
        acc0 = aself * lo2f(hvs.x);
        acc1 = aself * hi2f(hvs.x);
        acc2 = aself * lo2f(hvs.y);
        acc3 = aself * hi2f(hvs.y);
        for (int i = 0; i < c; i++) {
            int s = adj[o + i];
            float2 pp = pE[o + i];
            uint2 hv = Bu2[(size_t)s * 32 + hl];
            float a = (head ? pp.y : pp.x) * invh;
            acc0 += a * lo2f(hv.x);
            acc1 += a * hi2f(hv.x);
            acc2 += a * lo2f(hv.y);
            acc3 += a * hi2f(hv.y);
        }
    }

    // lane hl covers dwords 2hl,2hl+1 of the row = channels 4hl..4hl+3
    float4 bb4 = ((const float4*)biasF)[hl];
    float q0 = acc0 + bb4.x;
    float q1 = acc1 + bb4.y;
    float q2 = acc2 + bb4.z;
    float q3 = acc3 + bb4.w;
    if (dorelu) {
        q0 = fmaxf(q0, 0.f); q1 = fmaxf(q1, 0.f);
        q2 = fmaxf(q2, 0.f); q3 = fmaxf(q3, 0.f);
    }
    Au2[(size_t)node * 32 + hl] =
        make_uint2(((unsigned)f2us(q1) << 16) | f2us(q0),
                   ((unsigned)f2us(q3) << 16) | f2us(q2));
}

// ---------------- heads: ONE WAVE per graph, zero barriers ----------------
// Fuses the layer-2 aggregation for the graph-root node (the only consumed
// row) and runs the whole MLP chain with register-resident intermediates and
// shfl broadcasts.  lane = output channel; h channels live pairwise
// (lane -> ch 2*lane, 2*lane+1).
// NOTE: every __shfl here is executed with FULL exec (compute-both-then-
// select) — ds_bpermute reads from an EXEC-disabled source lane return 0,
// so a shfl inside a divergent ternary silently zeroes the broadcast
// (this was the R2 bug: head-1 alphas read p1 from inactive lanes 0..31).
template <int F32>
__device__ void heads_body(
    const unsigned* __restrict__ Brow, const float4* __restrict__ asadv,
    const int* __restrict__ offs, const int* __restrict__ bsums,
    const int* __restrict__ counts, const int* __restrict__ adj,
    const float* __restrict__ biasF, const int* __restrict__ node0,
    const void* __restrict__ x,
    const void* sW, const void* sb,
    const void* pW1, const void* pb1, const void* pW2, const void* pb2,
    const void* cW1, const void* cb1, const void* cW2, const void* cb2,
    const void* fW1, const void* fb1, const void* fW2, const void* fb2,
    const void* bW1, const void* bb1, const void* bW2, const void* bb2,
    const void* zW1, const void* zb1, const void* zW2, const void* zb2,
    void* __restrict__ outv) {
    int lane = threadIdx.x & 63;
    int g = blockIdx.x * 4 + (threadIdx.x >> 6);
    bf16* outb = (bf16*)outv;
    float* outf = (float*)outv;
#define STORE(idx, val) do { if (F32) outf[idx] = (val); else outb[idx] = __float2bfloat16(val); } while (0)

    int n0 = node0[g];

    // ---- fused layer-2 GAT aggregation at node n0 ----
    float4 self = asadv[n0];
    float es0 = __expf(leaky(self.x + self.z));
    float es1 = __expf(leaky(self.y + self.w));
    int o = offs[n0] + bsums[n0 >> 8];
    int c = counts[n0];

    int srcl = 0;
    float p0 = 0.f, p1 = 0.f;
    if (lane < c) {
        srcl = adj[o + lane];
        float4 av = asadv[srcl];
        p0 = __expf(leaky(av.x + self.z));
        p1 = __expf(leaky(av.y + self.w));
    }
    float sum0 = es0 + wsum64(p0);
    float sum1 = es1 + wsum64(p1);
    for (int base = 64; base < c; base += 64) {  // essentially never (avg degree ~12)
        float q0 = 0.f, q1 = 0.f;
        if (base + lane < c) {
            int s = adj[o + base + lane];
            float4 av = asadv[s];
            q0 = __expf(leaky(av.x + self.z));
            q1 = __expf(leaky(av.y + self.w));
        }
        sum0 += wsum64(q0);
        sum1 += wsum64(q1);
    }
    float inv0 = 1.f / (sum0 + 1e-16f);
    float inv1 = 1.f / (sum1 + 1e-16f);
    float invh = (lane < 32) ? inv0 : inv1;   // ch 2*lane: head0 iff lane<32

    unsigned hv0 = Brow[(size_t)n0 * 64 + lane];
    float aself = ((lane < 32) ? es0 : es1) * invh;
    float h0 = aself * lo2f(hv0);
    float h1 = aself * hi2f(hv0);
    int cc = min(c, 64);
    for (int j = 0; j < cc; ++j) {
        int s = __shfl(srcl, j);
        float a0 = __shfl(p0, j);          // full-exec broadcasts
        float a1 = __shfl(p1, j);
        float aa = ((lane < 32) ? a0 : a1) * invh;
        unsigned hv = Brow[(size_t)s * 64 + lane];
        h0 += aa * lo2f(hv);
        h1 += aa * hi2f(hv);
    }
    for (int j = 64; j < c; ++j) {  // never in practice
        int s = adj[o + j];
        float4 av = asadv[s];
        float aa = (lane < 32) ? __expf(leaky(av.x + self.z)) * inv0
                               : __expf(leaky(av.y + self.w)) * inv1;
        unsigned hv = Brow[(size_t)s * 64 + lane];
        h0 += aa * lo2f(hv);
        h1 += aa * hi2f(hv);
    }
    float2 bias2 = ((const float2*)biasF)[lane];
    h0 += bias2.x;  // ch 2*lane     (layer 2: no relu)
    h1 += bias2.y;  // ch 2*lane+1

    // dtype vector (raw input cols 0..21 of the root row)
    float rD = (lane < 22) ? LDWt<F32>(x, (size_t)n0 * 128 + lane) : 0.f;

    // ---- shared layer: zf = relu([h(128), dtype(22)] @ sW + sb) ----
    float p = 0.f;
    for (int i = 0; i < 64; ++i) {
        p += __shfl(h0, i) * LDWt<F32>(sW, (size_t)(2 * i) * 64 + lane);
        p += __shfl(h1, i) * LDWt<F32>(sW, (size_t)(2 * i + 1) * 64 + lane);
    }
    for (int i = 0; i < 22; ++i)
        p += __shfl(rD, i) * LDWt<F32>(sW, (size_t)(128 + i) * 64 + lane);
    float zf = fmaxf(p + LDWt<F32>(sb, lane), 0.f);

    // bin1[lane] holds bool_in[64+lane]: 22 dtype, 5 cat, 2 sf, 1 bool
    float bin1 = (lane < 22) ? rD : 0.f;

    // ---- ptr heads k=0..2 ----
#pragma unroll
    for (int k = 0; k < 3; ++k) {
        float pp = 0.f;
        for (int i = 0; i < 64; ++i)
            pp += __shfl(zf, i) * LDWt<F32>(pW1, (size_t)k * 4096 + (size_t)i * 64 + lane);
        float tt = fmaxf(pp + LDWt<F32>(pb1, k * 64 + lane), 0.f);
#pragma unroll
        for (int o2 = 0; o2 < 3; ++o2) {
            float v = wsum64(tt * LDWt<F32>(pW2, (size_t)k * 192 + (size_t)lane * 3 + o2));
            if (lane == 0) STORE(k * 768 + g * 3 + o2, v + LDWt<F32>(pb2, k * 3 + o2));
        }
    }

    // ---- cat head ----
    {
        float pp = 0.f;
        for (int i = 0; i < 64; ++i)
            pp += __shfl(zf, i) * LDWt<F32>(cW1, (size_t)i * 64 + lane);
        float tt = fmaxf(pp + LDWt<F32>(cb1, lane), 0.f);
#pragma unroll
        for (int o2 = 0; o2 < 5; ++o2) {
            float v = wsum64(tt * LDWt<F32>(cW2, (size_t)lane * 5 + o2)) + LDWt<F32>(cb2, o2);
            bin1 = (lane == 22 + o2) ? v : bin1;
            if (lane == 0) STORE(2304 + g * 5 + o2, v);
        }
    }

    // ---- signed/floating heads k=0,1 ----
#pragma unroll
    for (int k = 0; k < 2; ++k) {
        float pp = 0.f;
        for (int i = 0; i < 64; ++i)
            pp += __shfl(zf, i) * LDWt<F32>(fW1, (size_t)k * 4096 + (size_t)i * 64 + lane);
        float tt = fmaxf(pp + LDWt<F32>(fb1, k * 64 + lane), 0.f);
        float v = wsum64(tt * LDWt<F32>(fW2, k * 64 + lane)) + LDWt<F32>(fb2, k);
        bin1 = (lane == 27 + k) ? v : bin1;
        if (lane == 0) STORE(3584 + k * 256 + g, v);
    }

    // ---- bool head: 93 inputs = zf(64) + bin1[0..28] ----
    {
        float pp = 0.f;
        for (int i = 0; i < 64; ++i)
            pp += __shfl(zf, i) * LDWt<F32>(bW1, (size_t)i * 64 + lane);
        for (int i = 0; i < 29; ++i)
            pp += __shfl(bin1, i) * LDWt<F32>(bW1, (size_t)(64 + i) * 64 + lane);
        float tt = fmaxf(pp + LDWt<F32>(bb1, lane), 0.f);
        float v = wsum64(tt * LDWt<F32>(bW2, lane)) + LDWt<F32>(bb2, 0);
        bin1 = (lane == 29) ? v : bin1;
        if (lane == 0) STORE(4096 + g, v);
    }

    // ---- size head: 94 inputs = zf(64) + bin1[0..29] ----
    {
        float pp = 0.f;
        for (int i = 0; i < 64; ++i)
            pp += __shfl(zf, i) * LDWt<F32>(zW1, (size_t)i * 64 + lane);
        for (int i = 0; i < 30; ++i)
            pp += __shfl(bin1, i) * LDWt<F32>(zW1, (size_t)(64 + i) * 64 + lane);
        float tt = fmaxf(pp + LDWt<F32>(zb1, lane), 0.f);
#pragma unroll
        for (int o2 = 0; o2 < 8; ++o2) {
            float v = wsum64(tt * LDWt<F32>(zW2, (size_t)lane * 8 + o2));
            if (lane == 0) STORE(4352 + g * 8 + o2, v + LDWt<F32>(zb2, o2));
        }
    }
#undef STORE
}

__global__ __launch_bounds__(256) void k_heads2(
    const unsigned* __restrict__ Brow, const float4* __restrict__ asadv,
    const int* __restrict__ offs, const int* __restrict__ bsums,
    const int* __restrict__ counts, const int* __restrict__ adj,
    const float* __restrict__ biasF, const int* __restrict__ node0,
    const void* __restrict__ x,
    const void* sW, const void* sb,
    const void* pW1, const void* pb1, const void* pW2, const void* pb2,
    const void* cW1, const void* cb1, const void* cW2, const void* cb2,
    const void* fW1, const void* fb1, const void* fW2, const void* fb2,
    const void* bW1, const void* bb1, const void* bW2, const void* bb2,
    const void* zW1, const void* zb1, const void* zW2, const void* zb2,
    void* __restrict__ outv, const int* __restrict__ flag) {
    if (*flag)
        heads_body<1>(Brow, asadv, offs, bsums, counts, adj, biasF, node0, x,
                      sW, sb, pW1, pb1, pW2, pb2, cW1, cb1, cW2, cb2,
                      fW1, fb1, fW2, fb2, bW1, bb1, bW2, bb2,
                      zW1, zb1, zW2, zb2, outv);
    else
        heads_body<0>(Brow, asadv, offs, bsums, counts, adj, biasF, node0, x,
                      sW, sb, pW1, pb1, pW2, pb2, cW1, cb1, cW2, cb2,
                      fW1, fb1, fW2, fb2, bW1, bb1, bW2, bb2,
                      zW1, zb1, zW2, zb2, outv);
}

// ---------------- host ----------------

extern "C" void kernel_launch(void* const* d_in, const int* in_sizes, int n_in,
                              void* d_out, int out_size, void* d_ws, size_t ws_size,
                              hipStream_t stream) {
    const void* x     = d_in[0];
    const int*  ei    = (const int*)d_in[1];
    const int*  batch = (const int*)d_in[2];

    int N = in_sizes[0] / 128;
    int E = in_sizes[1] / 2;

    char* w = (char*)d_ws;
    float4* asad = (float4*)w;              w += (size_t)N * 16;
    unsigned short* A = (unsigned short*)w; w += (size_t)N * 128 * 2;
    unsigned short* B = (unsigned short*)w; w += (size_t)N * 128 * 2;
    float2* pE = (float2*)w;                w += (size_t)E * 8;
    unsigned short* Wt = (unsigned short*)w; w += 3 * 16384 * 2;
    float* asF = (float*)w;                 w += 384 * 4;
    float* adF = (float*)w;                 w += 384 * 4;
    float* bF = (float*)w;                  w += 384 * 4;
    int* offs = (int*)w;                    w += (size_t)N * 4;
    int* rank = (int*)w;                    w += (size_t)E * 4;
    int* adj = (int*)w;                     w += (size_t)E * 4;
    int* bsums = (int*)w;                   w += 512 * 4;
    int* node0 = (int*)w;                   w += 256 * 4;
    // ---- contiguous zero-region (single memset) ----
    int* counts = (int*)w;                  w += (size_t)N * 4;
    int* flag = (int*)w;                    w += 64;
    unsigned char* flag1 = (unsigned char*)w; w += (size_t)N;
    unsigned char* flag2 = (unsigned char*)w; w += (size_t)N;

    int nb = (N + 255) / 256;
    int nbx = (N * 128 + 255) / 256;
    int nbE = (E + 255) / 256;

    hipMemsetAsync(counts, 0, (size_t)N * 4 + 64 + (size_t)N * 2, stream);

    k_detect<<<16, 256, 0, stream>>>(x, flag);

    k_prep_fused<<<nbx + 194 + nb, 256, 0, stream>>>(
        x, A, N * 128, d_in[3], Wt, d_in[4], d_in[5], d_in[6],
        asF, adF, bF, batch, node0, N, flag, nbx, nb);

    // layer-0 GEMM fused with edge histogram + mark2 (atomic stream overlaps MFMA)
    int gemmBlocks = (N + 63) / 64;
    k_gemm0_hist<<<nbE + 1 + gemmBlocks, 256, 0, stream>>>(
        A, Wt, B, asad, asF, adF, N, ei, counts, rank, batch, node0, flag2, E, nbE);

    k_scan1<<<nb, 256, 0, stream>>>(counts, offs, bsums, N);
    k_scan2<<<1, 512, 0, stream>>>(bsums, nb);

    // scatter + mark1 + flag1 self-propagate in one kernel
    int sBlocks = 8 * nbE;
    k_scatter_mark<<<sBlocks + nbE + nb, 256, 0, stream>>>(
        ei, offs, bsums, rank, adj, flag2, flag1, E, N, sBlocks, nbE);

    // agg grid: 2 nodes per wave, 4 waves per block
    int nwaves = (N + 1) / 2;
    int aggblocks = (nwaves + 3) / 4;

    // layer 0 agg: only where layer-1 projection is needed (flag1)
    k_gat_agg<<<aggblocks, 256, 0, stream>>>(
        (const uint2*)B, asad, offs, bsums, counts, adj, bF, (uint2*)A, pE, N, 1, flag1);

    // layer 1: gemm on flag1 rows, agg only where layer-2 projection is needed (flag2)
    k_gemm_mfma<<<gemmBlocks, 256, 0, stream>>>(
        A, Wt + 16384, B, asad, asF + 128, adF + 128, N, flag1);
    k_gat_agg<<<aggblocks, 256, 0, stream>>>(
        (const uint2*)B, asad, offs, bsums, counts, adj, bF + 128, (uint2*)A, pE, N, 1, flag2);

    // layer 2: gemm on flag2 rows; the final aggregation (256 root nodes) is
    // fused into the heads kernel.
    k_gemm_mfma<<<gemmBlocks, 256, 0, stream>>>(
        A, Wt + 2 * 16384, B, asad, asF + 256, adF + 256, N, flag2);

    k_heads2<<<64, 256, 0, stream>>>(
        (const unsigned*)B, asad, offs, bsums, counts, adj, bF + 256, node0, x,
        d_in[7], d_in[8], d_in[9], d_in[10], d_in[11], d_in[12],
        d_in[13], d_in[14], d_in[15], d_in[16],
        d_in[17], d_in[18], d_in[19], d_in[20],
        d_in[21], d_in[22], d_in[23], d_in[24],
        d_in[25], d_in[26], d_in[27], d_in[28],
        d_out, flag);
}

// Round 4
// 408.794 us; speedup vs baseline: 1.4318x; 1.0594x over previous
//
#include <hip/hip_runtime.h>
#include <hip/hip_bf16.h>

typedef __hip_bfloat16 bf16;
typedef __attribute__((ext_vector_type(8))) short short8;
typedef __attribute__((ext_vector_type(4))) float floatx4;

__device__ __forceinline__ float b2f(bf16 v) { return __bfloat162float(v); }
__device__ __forceinline__ float us2f(unsigned short u) {
    return __uint_as_float(((unsigned)u) << 16);
}
__device__ __forceinline__ unsigned short f2us(float f) {
    bf16 h = __float2bfloat16(f);
    return *(unsigned short*)&h;
}
__device__ __forceinline__ float lo2f(unsigned hv) { return __uint_as_float(hv << 16); }
__device__ __forceinline__ float hi2f(unsigned hv) { return __uint_as_float(hv & 0xffff0000u); }
__device__ __forceinline__ float leaky(float v) { return v > 0.f ? v : 0.2f * v; }

// flag-aware raw-input read by ELEMENT index: f32==1 -> f32 storage, else bf16
__device__ __forceinline__ float ldw(const void* p, size_t i, int f32) {
    return f32 ? ((const float*)p)[i] : b2f(((const bf16*)p)[i]);
}

template <int F32>
__device__ __forceinline__ float LDWt(const void* p, size_t i) {
    return F32 ? ((const float*)p)[i] : b2f(((const bf16*)p)[i]);
}

// OR of the 16 per-block detect partials (no atomics, no pre-zero needed)
__device__ __forceinline__ int or16(const int* f) {
    int r = 0;
#pragma unroll
    for (int j = 0; j < 16; j++) r |= f[j];
    return r;
}

// full-wave (64-lane) butterfly sum; every lane ends with the total
__device__ __forceinline__ float wsum64(float v) {
#pragma unroll
    for (int m = 1; m <= 32; m <<= 1) v += __shfl_xor(v, m);
    return v;
}

// ---------------- dtype detection + workspace zeroing (fused, first kernel) ----
// blocks 0..15: sample x[0..4095]; block b plain-writes flagv[b] (no pre-zero).
// remaining blocks: zero the contiguous {counts, flag1, flag2, rootb} region.
__global__ void k_detect_zero(const void* x, int* flagv, char* zbase, size_t zbytes) {
    int b = blockIdx.x;
    int t = threadIdx.x;
    if (b < 16) {
        __shared__ int sbad;
        if (t == 0) sbad = 0;
        __syncthreads();
        float v = b2f(((const bf16*)x)[b * 256 + t]);
        if (!(fabsf(v) < 1e10f)) sbad = 1;  // benign same-value race
        __syncthreads();
        if (t == 0) flagv[b] = sbad;
    } else {
        size_t off = (size_t)(b - 16) * 4096 + (size_t)t * 16;
        if (off < zbytes) *(uint4*)(zbase + off) = make_uint4(0u, 0u, 0u, 0u);
    }
}

// ---------------- fused prep: x->bf16 (VECTORIZED), W transpose, small weights,
// node0 + root marks ----
__global__ void k_prep_fused(const void* __restrict__ x, unsigned short* __restrict__ Ab,
                             int nvec,
                             const void* __restrict__ gw, unsigned short* __restrict__ Wt,
                             const void* as_, const void* ad_, const void* b_,
                             float* asF, float* adF, float* bF,
                             const int* __restrict__ batch, int* __restrict__ node0,
                             unsigned char* __restrict__ rootb,
                             unsigned char* __restrict__ flag2, int N,
                             const int* __restrict__ flagv, int nbx8) {
    int b = blockIdx.x;
    int t = threadIdx.x;
    int f32 = or16(flagv);
    if (b < nbx8) {
        // 8 elements per thread.  bf16 storage: pure uint4 memcpy.
        int i = b * 256 + t;
        if (i < nvec) {
            if (!f32) {
                ((uint4*)Ab)[i] = ((const uint4*)x)[i];
            } else {
                float4 a = ((const float4*)x)[2 * i];
                float4 c = ((const float4*)x)[2 * i + 1];
                uint4 o;
                o.x = ((unsigned)f2us(a.y) << 16) | f2us(a.x);
                o.y = ((unsigned)f2us(a.w) << 16) | f2us(a.z);
                o.z = ((unsigned)f2us(c.y) << 16) | f2us(c.x);
                o.w = ((unsigned)f2us(c.w) << 16) | f2us(c.z);
                ((uint4*)Ab)[i] = o;
            }
        }
    } else if (b < nbx8 + 192) {
        int i = (b - nbx8) * 256 + t;  // exactly 3*16384
        int l = i >> 14, rem = i & 16383, n = rem >> 7, k = rem & 127;
        Wt[i] = f2us(ldw(gw, (size_t)l * 16384 + (size_t)k * 128 + n, f32));
    } else if (b < nbx8 + 194) {
        int i = (b - nbx8 - 192) * 256 + t;
        if (i < 384) {
            asF[i] = ldw(as_, i, f32);
            adF[i] = ldw(ad_, i, f32);
            bF[i] = ldw(b_, i, f32);
        }
    } else {
        int i = (b - nbx8 - 194) * 256 + t;
        if (i < N) {
            int bb = batch[i];
            if (i == 0 || batch[i - 1] != bb) {
                node0[bb] = i;
                rootb[i] = 1;   // root bitmap (stable input to the mark edge-scan)
                flag2[i] = 1;   // roots are always in the layer-2 frontier
            }
        }
    }
}

// ---------------- prefix scans ----------------
__global__ void k_scan1(const int* __restrict__ counts, int* __restrict__ offs,
                        int* __restrict__ bsums, int n) {
    __shared__ int s[256];
    int tid = threadIdx.x;
    int i = blockIdx.x * 256 + tid;
    int v = (i < n) ? counts[i] : 0;
    s[tid] = v;
    __syncthreads();
    for (int d = 1; d < 256; d <<= 1) {
        int t = (tid >= d) ? s[tid - d] : 0;
        __syncthreads();
        s[tid] += t;
        __syncthreads();
    }
    int incl = s[tid];
    if (i < n) offs[i] = incl - v;
    if (tid == 255) bsums[blockIdx.x] = incl;
}

__global__ void k_scan2(int* __restrict__ bsums, int nb) {
    __shared__ int s[512];
    int tid = threadIdx.x;
    int v = (tid < nb) ? bsums[tid] : 0;
    s[tid] = v;
    __syncthreads();
    for (int d = 1; d < 512; d <<= 1) {
        int t = (tid >= d) ? s[tid - d] : 0;
        __syncthreads();
        s[tid] += t;
        __syncthreads();
    }
    bsums[tid] = s[tid] - v;
}

// ---------------- frontier mark 1: flag1 = flag2 ∪ srcs(flag2) ----------------
__global__ void k_mark1(const int* __restrict__ ei, const unsigned char* __restrict__ flag2,
                        unsigned char* __restrict__ flag1, int E, int N, int eBlocks) {
    int b = blockIdx.x;
    if (b < eBlocks) {
        int e = b * 256 + threadIdx.x;
        if (e < E && flag2[ei[E + e]]) flag1[ei[e]] = 1;
    } else {
        int i = (b - eBlocks) * 256 + threadIdx.x;
        if (i < N && flag2[i]) flag1[i] = 1;
    }
}

// ---------------- masked histogram: atomics ONLY for edges into flag1 dsts ----
// (~33% of E -> ~3x fewer memory-side atomic RMWs, the measured 750 GB/s jam)
__global__ void k_hist_masked(const int* __restrict__ ei, const unsigned char* __restrict__ flag1,
                              int* __restrict__ counts, int* __restrict__ rank, int E) {
    int e = blockIdx.x * blockDim.x + threadIdx.x;
    if (e < E) {
        int d = ei[E + e];
        if (flag1[d]) rank[e] = atomicAdd(&counts[d], 1);
    }
}

// ---------------- masked XCD-partitioned scatter ----------------
__global__ void k_scatter8(const int* __restrict__ ei, const int* __restrict__ offs,
                           const int* __restrict__ bsums, const int* __restrict__ rank,
                           const unsigned char* __restrict__ flag1,
                           int* __restrict__ adj, int E, int N) {
    int xcd = blockIdx.x & 7;
    int e = (blockIdx.x >> 3) * 256 + threadIdx.x;
    if (e >= E) return;
    int d = ei[E + e];
    if (!flag1[d]) return;
    int lo = (int)(((long long)N * xcd) >> 3);
    int hi = (int)(((long long)N * (xcd + 1)) >> 3);
    if (d >= lo && d < hi) adj[offs[d] + bsums[d >> 8] + rank[e]] = ei[e];
}

// ---------------- MFMA GEMM body + fused attention scalars ----------------
__device__ __forceinline__ void gemm_body(
    const unsigned short* __restrict__ Ab, const unsigned short* __restrict__ Wt,
    unsigned short* __restrict__ Bb, float4* __restrict__ asadv,
    const float* __restrict__ asF, const float* __restrict__ adF, int N,
    const unsigned char* __restrict__ rflag, int bb) {
    __shared__ unsigned short Cs[64 * 136];

    int t = threadIdx.x;
    int r0 = bb * 64;

    int lane = t & 63;
    int w = t >> 6;
    int ln = lane & 15;
    int quad = lane >> 4;

    int arow = r0 + w * 16 + ln;
    bool valid = (arow < N) && (!rflag || rflag[arow]);
    bool wave_active = __any((int)valid);

    if (wave_active) {
        const unsigned short* ap = Ab + (size_t)arow * 128 + quad * 8;

        short8 afrag[4];
        if (valid) {
#pragma unroll
            for (int kt = 0; kt < 4; kt++)
                afrag[kt] = *(const short8*)(ap + kt * 32);
        } else {
#pragma unroll
            for (int kt = 0; kt < 4; kt++)
                afrag[kt] = (short8){0, 0, 0, 0, 0, 0, 0, 0};
        }

        floatx4 acc[8];
#pragma unroll
        for (int nt = 0; nt < 8; nt++) acc[nt] = (floatx4){0.f, 0.f, 0.f, 0.f};

#pragma unroll
        for (int nt = 0; nt < 8; nt++) {
            const unsigned short* wp = Wt + (size_t)(nt * 16 + ln) * 128 + quad * 8;
#pragma unroll
            for (int kt = 0; kt < 4; kt++) {
                short8 bfrag = *(const short8*)(wp + kt * 32);
                acc[nt] = __builtin_amdgcn_mfma_f32_16x16x32_bf16(afrag[kt], bfrag, acc[nt], 0, 0, 0);
            }
        }

        float as0[4] = {0, 0, 0, 0}, as1[4] = {0, 0, 0, 0};
        float ad0[4] = {0, 0, 0, 0}, ad1[4] = {0, 0, 0, 0};
#pragma unroll
        for (int nt = 0; nt < 8; nt++) {
            float asc = asF[nt * 16 + ln];
            float adc = adF[nt * 16 + ln];
#pragma unroll
            for (int r = 0; r < 4; r++) {
                float v = acc[nt][r];
                Cs[(w * 16 + quad * 4 + r) * 136 + nt * 16 + ln] = f2us(v);
                if (nt < 4) { as0[r] += v * asc; ad0[r] += v * adc; }
                else        { as1[r] += v * asc; ad1[r] += v * adc; }
            }
        }
#pragma unroll
        for (int mask = 1; mask <= 8; mask <<= 1) {
#pragma unroll
            for (int r = 0; r < 4; r++) {
                as0[r] += __shfl_xor(as0[r], mask);
                as1[r] += __shfl_xor(as1[r], mask);
                ad0[r] += __shfl_xor(ad0[r], mask);
                ad1[r] += __shfl_xor(ad1[r], mask);
            }
        }
        if (ln == 0) {
#pragma unroll
            for (int r = 0; r < 4; r++) {
                int row = r0 + w * 16 + quad * 4 + r;
                if (row < N && (!rflag || rflag[row]))
                    asadv[row] = make_float4(as0[r], as1[r], ad0[r], ad1[r]);
            }
        }
    }
    __syncthreads();

    {
        int row = t >> 2;
        int grow = r0 + row;
        int cseg = (t & 3) * 32;
        if (grow < N && (!rflag || rflag[grow])) {
            const short8* srcp = (const short8*)&Cs[row * 136 + cseg];
            short8* dstp = (short8*)&Bb[(size_t)grow * 128 + cseg];
#pragma unroll
            for (int u = 0; u < 4; u++) dstp[u] = srcp[u];
        }
    }
}

// layers 1,2: plain GEMM with row mask
__global__ __launch_bounds__(256) void k_gemm_mfma(
    const unsigned short* __restrict__ Ab, const unsigned short* __restrict__ Wt,
    unsigned short* __restrict__ Bb, float4* __restrict__ asadv,
    const float* __restrict__ asF, const float* __restrict__ adF, int N,
    const unsigned char* __restrict__ rflag) {
    gemm_body(Ab, Wt, Bb, asadv, asF, adF, N, rflag, blockIdx.x);
}

// layer 0: GEMM fused with the mark2 edge scan (flag2[src] |= rootb[dst]).
// Clean coalesced reads only — no atomics — so it genuinely overlaps MFMA.
__global__ __launch_bounds__(256) void k_gemm0_mark(
    const unsigned short* __restrict__ Ab, const unsigned short* __restrict__ Wt,
    unsigned short* __restrict__ Bb, float4* __restrict__ asadv,
    const float* __restrict__ asF, const float* __restrict__ adF, int N,
    const int* __restrict__ ei, const unsigned char* __restrict__ rootb,
    unsigned char* __restrict__ flag2, int E, int markBlocks) {
    int b = blockIdx.x;
    if (b < markBlocks) {
        int e = b * 256 + threadIdx.x;
        if (e < E) {
            int d = ei[E + e];
            if (rootb[d]) flag2[ei[e]] = 1;
        }
        return;
    }
    gemm_body(Ab, Wt, Bb, asadv, asF, adF, N, nullptr, b - markBlocks);
}

// ---------------- GAT aggregation: TWO nodes per wave, depth-4 pipeline ----------------
__global__ void k_gat_agg(const uint2* __restrict__ Bu2, const float4* __restrict__ asadv,
                          const int* __restrict__ offs, const int* __restrict__ bsums,
                          const int* __restrict__ counts,
                          const int* __restrict__ adj, const float* __restrict__ biasF,
                          uint2* __restrict__ Au2, float2* __restrict__ pE,
                          int n, int dorelu,
                          const unsigned char* __restrict__ nflag) {
    int wave = (blockIdx.x * blockDim.x + threadIdx.x) >> 6;
    int lane = threadIdx.x & 63;
    int hl = lane & 31;          // lane within node-half
    int hb = lane & 32;          // shfl broadcast base for this half
    int node = wave * 2 + (lane >> 5);
    if (node >= n) return;
    if (nflag && !nflag[node]) return;  // pruned row: half-wave exits (shfls stay in-half)
    int head = hl >> 4;          // channels 4hl..4hl+3

    float4 self = asadv[node];
    float ad0 = self.z, ad1 = self.w;
    float es0 = __expf(leaky(self.x + ad0));
    float es1 = __expf(leaky(self.y + ad1));

    int o = offs[node] + bsums[node >> 8];
    int c = counts[node];
    uint2 hvs = Bu2[(size_t)node * 32 + hl];
    float acc0, acc1, acc2, acc3;

    if (c <= 32) {
        // ---- fast path ----
        int src_r = 0;
        float p0 = 0.f, p1 = 0.f;
        if (hl < c) {
            src_r = adj[o + hl];
            float4 av = asadv[src_r];
            p0 = __expf(leaky(av.x + ad0));
            p1 = __expf(leaky(av.y + ad1));
        }
        float t0 = p0, t1 = p1;
#pragma unroll
        for (int mask = 1; mask <= 16; mask <<= 1) {
            t0 += __shfl_xor(t0, mask);
            t1 += __shfl_xor(t1, mask);
        }
        float inv0 = 1.f / (es0 + t0 + 1e-16f);
        float inv1 = 1.f / (es1 + t1 + 1e-16f);
        p0 *= inv0;                       // pre-scaled alphas
        p1 *= inv1;
        float aself = head ? es1 * inv1 : es0 * inv0;
        acc0 = aself * lo2f(hvs.x);
        acc1 = aself * hi2f(hvs.x);
        acc2 = aself * lo2f(hvs.y);
        acc3 = aself * hi2f(hvs.y);

        // prologue: prefetch rows for edges 0..3
        uint2 hq[4];
#pragma unroll
        for (int j = 0; j < 4; j++) {
            int s2 = __shfl(src_r, hb + j);
            hq[j] = make_uint2(0u, 0u);
            if (j < c) hq[j] = Bu2[(size_t)s2 * 32 + hl];
        }

        for (int base = 0; base < c; base += 4) {
            uint2 cur[4];
            float av4[4];
#pragma unroll
            for (int j = 0; j < 4; j++) {
                cur[j] = hq[j];
                int idx2 = (base + j) & 31;
                float a0 = __shfl(p0, hb + idx2);   // both heads broadcast (full exec);
                float a1 = __shfl(p1, hb + idx2);   // consumer selects its head
                float a = head ? a1 : a0;
                av4[j] = (base + j < c) ? a : 0.f;  // tail guard (stale cur is finite)
            }
            // issue next 4 loads before consuming cur
#pragma unroll
            for (int j = 0; j < 4; j++) {
                int nx = base + 4 + j;
                int s2 = __shfl(src_r, hb + (nx & 31));
                if (nx < c) hq[j] = Bu2[(size_t)s2 * 32 + hl];
            }
#pragma unroll
            for (int j = 0; j < 4; j++) {
                acc0 += av4[j] * lo2f(cur[j].x);
                acc1 += av4[j] * hi2f(cur[j].x);
                acc2 += av4[j] * lo2f(cur[j].y);
                acc3 += av4[j] * hi2f(cur[j].y);
            }
        }
    } else {
        // ---- slow path (rare, c>32): alphas staged in global scratch ----
        float sum0 = es0, sum1 = es1;
        for (int base = 0; base < c; base += 32) {
            int i = base + hl;
            float p0 = 0.f, p1 = 0.f;
            if (i < c) {
                int s = adj[o + i];
                float4 av = asadv[s];
                p0 = __expf(leaky(av.x + ad0));
                p1 = __expf(leaky(av.y + ad1));
                pE[o + i] = make_float2(p0, p1);
            }
            float t0 = p0, t1 = p1;
#pragma unroll
            for (int mask = 1; mask <= 16; mask <<= 1) {
                t0 += __shfl_xor(t0, mask);
                t1 += __shfl_xor(t1, mask);
            }
            sum0 += t0; sum1 += t1;
        }
        float inv0 = 1.f / (sum0 + 1e-16f);
        float inv1 = 1.f / (sum1 + 1e-16f);
        float aself = head ? es1 * inv1 : es0 * inv0;
        float invh = head ? inv1 : inv0;
        acc0 = aself * lo2f(hvs.x);
        acc1 = aself * hi2f(hvs.x);
        acc2 = aself * lo2f(hvs.y);
        acc3 = aself * hi2f(hvs.y);
        for (int i = 0; i < c; i++) {
            int s = adj[o + i];
            float2 pp = pE[o + i];
            uint2 hv = Bu2[(size_t)s * 32 + hl];
            float a = (head ? pp.y : pp.x) * invh;
            acc0 += a * lo2f(hv.x);
            acc1 += a * hi2f(hv.x);
            acc2 += a * lo2f(hv.y);
            acc3 += a * hi2f(hv.y);
        }
    }

    // lane hl covers dwords 2hl,2hl+1 of the row = channels 4hl..4hl+3
    float4 bb4 = ((const float4*)biasF)[hl];
    float q0 = acc0 + bb4.x;
    float q1 = acc1 + bb4.y;
    float q2 = acc2 + bb4.z;
    float q3 = acc3 + bb4.w;
    if (dorelu) {
        q0 = fmaxf(q0, 0.f); q1 = fmaxf(q1, 0.f);
        q2 = fmaxf(q2, 0.f); q3 = fmaxf(q3, 0.f);
    }
    Au2[(size_t)node * 32 + hl] =
        make_uint2(((unsigned)f2us(q1) << 16) | f2us(q0),
                   ((unsigned)f2us(q3) << 16) | f2us(q2));
}

// ---------------- heads: ONE WAVE per graph, zero barriers ----------------
// (passed R3 — all __shfl broadcasts run with FULL exec: compute-both-then-
// select; ds_bpermute from an exec-disabled source lane returns 0.)
template <int F32>
__device__ void heads_body(
    const unsigned* __restrict__ Brow, const float4* __restrict__ asadv,
    const int* __restrict__ offs, const int* __restrict__ bsums,
    const int* __restrict__ counts, const int* __restrict__ adj,
    const float* __restrict__ biasF, const int* __restrict__ node0,
    const void* __restrict__ x,
    const void* sW, const void* sb,
    const void* pW1, const void* pb1, const void* pW2, const void* pb2,
    const void* cW1, const void* cb1, const void* cW2, const void* cb2,
    const void* fW1, const void* fb1, const void* fW2, const void* fb2,
    const void* bW1, const void* bb1, const void* bW2, const void* bb2,
    const void* zW1, const void* zb1, const void* zW2, const void* zb2,
    void* __restrict__ outv) {
    int lane = threadIdx.x & 63;
    int g = blockIdx.x * 4 + (threadIdx.x >> 6);
    bf16* outb = (bf16*)outv;
    float* outf = (float*)outv;
#define STORE(idx, val) do { if (F32) outf[idx] = (val); else outb[idx] = __float2bfloat16(val); } while (0)

    int n0 = node0[g];

    // ---- fused layer-2 GAT aggregation at node n0 ----
    float4 self = asadv[n0];
    float es0 = __expf(leaky(self.x + self.z));
    float es1 = __expf(leaky(self.y + self.w));
    int o = offs[n0] + bsums[n0 >> 8];
    int c = counts[n0];

    int srcl = 0;
    float p0 = 0.f, p1 = 0.f;
    if (lane < c) {
        srcl = adj[o + lane];
        float4 av = asadv[srcl];
        p0 = __expf(leaky(av.x + self.z));
        p1 = __expf(leaky(av.y + self.w));
    }
    float sum0 = es0 + wsum64(p0);
    float sum1 = es1 + wsum64(p1);
    for (int base = 64; base < c; base += 64) {  // essentially never (avg degree ~12)
        float q0 = 0.f, q1 = 0.f;
        if (base + lane < c) {
            int s = adj[o + base + lane];
            float4 av = asadv[s];
            q0 = __expf(leaky(av.x + self.z));
            q1 = __expf(leaky(av.y + self.w));
        }
        sum0 += wsum64(q0);
        sum1 += wsum64(q1);
    }
    float inv0 = 1.f / (sum0 + 1e-16f);
    float inv1 = 1.f / (sum1 + 1e-16f);
    float invh = (lane < 32) ? inv0 : inv1;   // ch 2*lane: head0 iff lane<32

    unsigned hv0 = Brow[(size_t)n0 * 64 + lane];
    float aself = ((lane < 32) ? es0 : es1) * invh;
    float h0 = aself * lo2f(hv0);
    float h1 = aself * hi2f(hv0);
    int cc = min(c, 64);
    for (int j = 0; j < cc; ++j) {
        int s = __shfl(srcl, j);
        float a0 = __shfl(p0, j);          // full-exec broadcasts
        float a1 = __shfl(p1, j);
        float aa = ((lane < 32) ? a0 : a1) * invh;
        unsigned hv = Brow[(size_t)s * 64 + lane];
        h0 += aa * lo2f(hv);
        h1 += aa * hi2f(hv);
    }
    for (int j = 64; j < c; ++j) {  // never in practice
        int s = adj[o + j];
        float4 av = asadv[s];
        float aa = (lane < 32) ? __expf(leaky(av.x + self.z)) * inv0
                               : __expf(leaky(av.y + self.w)) * inv1;
        unsigned hv = Brow[(size_t)s * 64 + lane];
        h0 += aa * lo2f(hv);
        h1 += aa * hi2f(hv);
    }
    float2 bias2 = ((const float2*)biasF)[lane];
    h0 += bias2.x;  // ch 2*lane     (layer 2: no relu)
    h1 += bias2.y;  // ch 2*lane+1

    // dtype vector (raw input cols 0..21 of the root row)
    float rD = (lane < 22) ? LDWt<F32>(x, (size_t)n0 * 128 + lane) : 0.f;

    // ---- shared layer: zf = relu([h(128), dtype(22)] @ sW + sb) ----
    float p = 0.f;
    for (int i = 0; i < 64; ++i) {
        p += __shfl(h0, i) * LDWt<F32>(sW, (size_t)(2 * i) * 64 + lane);
        p += __shfl(h1, i) * LDWt<F32>(sW, (size_t)(2 * i + 1) * 64 + lane);
    }
    for (int i = 0; i < 22; ++i)
        p += __shfl(rD, i) * LDWt<F32>(sW, (size_t)(128 + i) * 64 + lane);
    float zf = fmaxf(p + LDWt<F32>(sb, lane), 0.f);

    // bin1[lane] holds bool_in[64+lane]: 22 dtype, 5 cat, 2 sf, 1 bool
    float bin1 = (lane < 22) ? rD : 0.f;

    // ---- ptr heads k=0..2 ----
#pragma unroll
    for (int k = 0; k < 3; ++k) {
        float pp = 0.f;
        for (int i = 0; i < 64; ++i)
            pp += __shfl(zf, i) * LDWt<F32>(pW1, (size_t)k * 4096 + (size_t)i * 64 + lane);
        float tt = fmaxf(pp + LDWt<F32>(pb1, k * 64 + lane), 0.f);
#pragma unroll
        for (int o2 = 0; o2 < 3; ++o2) {
            float v = wsum64(tt * LDWt<F32>(pW2, (size_t)k * 192 + (size_t)lane * 3 + o2));
            if (lane == 0) STORE(k * 768 + g * 3 + o2, v + LDWt<F32>(pb2, k * 3 + o2));
        }
    }

    // ---- cat head ----
    {
        float pp = 0.f;
        for (int i = 0; i < 64; ++i)
            pp += __shfl(zf, i) * LDWt<F32>(cW1, (size_t)i * 64 + lane);
        float tt = fmaxf(pp + LDWt<F32>(cb1, lane), 0.f);
#pragma unroll
        for (int o2 = 0; o2 < 5; ++o2) {
            float v = wsum64(tt * LDWt<F32>(cW2, (size_t)lane * 5 + o2)) + LDWt<F32>(cb2, o2);
            bin1 = (lane == 22 + o2) ? v : bin1;
            if (lane == 0) STORE(2304 + g * 5 + o2, v);
        }
    }

    // ---- signed/floating heads k=0,1 ----
#pragma unroll
    for (int k = 0; k < 2; ++k) {
        float pp = 0.f;
        for (int i = 0; i < 64; ++i)
            pp += __shfl(zf, i) * LDWt<F32>(fW1, (size_t)k * 4096 + (size_t)i * 64 + lane);
        float tt = fmaxf(pp + LDWt<F32>(fb1, k * 64 + lane), 0.f);
        float v = wsum64(tt * LDWt<F32>(fW2, k * 64 + lane)) + LDWt<F32>(fb2, k);
        bin1 = (lane == 27 + k) ? v : bin1;
        if (lane == 0) STORE(3584 + k * 256 + g, v);
    }

    // ---- bool head: 93 inputs = zf(64) + bin1[0..28] ----
    {
        float pp = 0.f;
        for (int i = 0; i < 64; ++i)
            pp += __shfl(zf, i) * LDWt<F32>(bW1, (size_t)i * 64 + lane);
        for (int i = 0; i < 29; ++i)
            pp += __shfl(bin1, i) * LDWt<F32>(bW1, (size_t)(64 + i) * 64 + lane);
        float tt = fmaxf(pp + LDWt<F32>(bb1, lane), 0.f);
        float v = wsum64(tt * LDWt<F32>(bW2, lane)) + LDWt<F32>(bb2, 0);
        bin1 = (lane == 29) ? v : bin1;
        if (lane == 0) STORE(4096 + g, v);
    }

    // ---- size head: 94 inputs = zf(64) + bin1[0..29] ----
    {
        float pp = 0.f;
        for (int i = 0; i < 64; ++i)
            pp += __shfl(zf, i) * LDWt<F32>(zW1, (size_t)i * 64 + lane);
        for (int i = 0; i < 30; ++i)
            pp += __shfl(bin1, i) * LDWt<F32>(zW1, (size_t)(64 + i) * 64 + lane);
        float tt = fmaxf(pp + LDWt<F32>(zb1, lane), 0.f);
#pragma unroll
        for (int o2 = 0; o2 < 8; ++o2) {
            float v = wsum64(tt * LDWt<F32>(zW2, (size_t)lane * 8 + o2));
            if (lane == 0) STORE(4352 + g * 8 + o2, v + LDWt<F32>(zb2, o2));
        }
    }
#undef STORE
}

__global__ __launch_bounds__(256) void k_heads2(
    const unsigned* __restrict__ Brow, const float4* __restrict__ asadv,
    const int* __restrict__ offs, const int* __restrict__ bsums,
    const int* __restrict__ counts, const int* __restrict__ adj,
    const float* __restrict__ biasF, const int* __restrict__ node0,
    const void* __restrict__ x,
    const void* sW, const void* sb,
    const void* pW1, const void* pb1, const void* pW2, const void* pb2,
    const void* cW1, const void* cb1, const void* cW2, const void* cb2,
    const void* fW1, const void* fb1, const void* fW2, const void* fb2,
    const void* bW1, const void* bb1, const void* bW2, const void* bb2,
    const void* zW1, const void* zb1, const void* zW2, const void* zb2,
    void* __restrict__ outv, const int* __restrict__ flagv) {
    if (or16(flagv))
        heads_body<1>(Brow, asadv, offs, bsums, counts, adj, biasF, node0, x,
                      sW, sb, pW1, pb1, pW2, pb2, cW1, cb1, cW2, cb2,
                      fW1, fb1, fW2, fb2, bW1, bb1, bW2, bb2,
                      zW1, zb1, zW2, zb2, outv);
    else
        heads_body<0>(Brow, asadv, offs, bsums, counts, adj, biasF, node0, x,
                      sW, sb, pW1, pb1, pW2, pb2, cW1, cb1, cW2, cb2,
                      fW1, fb1, fW2, fb2, bW1, bb1, bW2, bb2,
                      zW1, zb1, zW2, zb2, outv);
}

// ---------------- host ----------------

extern "C" void kernel_launch(void* const* d_in, const int* in_sizes, int n_in,
                              void* d_out, int out_size, void* d_ws, size_t ws_size,
                              hipStream_t stream) {
    const void* x     = d_in[0];
    const int*  ei    = (const int*)d_in[1];
    const int*  batch = (const int*)d_in[2];

    int N = in_sizes[0] / 128;
    int E = in_sizes[1] / 2;

    char* w = (char*)d_ws;
    float4* asad = (float4*)w;              w += (size_t)N * 16;
    unsigned short* A = (unsigned short*)w; w += (size_t)N * 128 * 2;
    unsigned short* B = (unsigned short*)w; w += (size_t)N * 128 * 2;
    float2* pE = (float2*)w;                w += (size_t)E * 8;
    unsigned short* Wt = (unsigned short*)w; w += 3 * 16384 * 2;
    float* asF = (float*)w;                 w += 384 * 4;
    float* adF = (float*)w;                 w += 384 * 4;
    float* bF = (float*)w;                  w += 384 * 4;
    int* offs = (int*)w;                    w += (size_t)N * 4;
    int* rank = (int*)w;                    w += (size_t)E * 4;
    int* adj = (int*)w;                     w += (size_t)E * 4;
    int* bsums = (int*)w;                   w += 512 * 4;
    int* node0 = (int*)w;                   w += 256 * 4;
    // ---- contiguous zero-region (zeroed by k_detect_zero) ----
    char* zbase = w;
    int* counts = (int*)w;                  w += (size_t)N * 4;
    unsigned char* flag1 = (unsigned char*)w; w += (size_t)N;
    unsigned char* flag2 = (unsigned char*)w; w += (size_t)N;
    unsigned char* rootb = (unsigned char*)w; w += (size_t)N;
    size_t zbytes = (size_t)N * 7;
    int* flagv = (int*)w;                   w += 64;  // 16 per-block detect partials

    int nb = (N + 255) / 256;
    int nvec = N * 16;               // N*128/8
    int nbx8 = (nvec + 255) / 256;
    int nbE = (E + 255) / 256;
    int gemmBlocks = (N + 63) / 64;
    int zBlocks = (int)((zbytes + 4095) / 4096);

    // dtype probe + workspace zeroing (no memset launch, no pre-zeroed flag)
    k_detect_zero<<<16 + zBlocks, 256, 0, stream>>>(x, flagv, zbase, zbytes);

    // prep: vectorized x copy/convert, Wt transpose, small weights, node0+roots
    k_prep_fused<<<nbx8 + 194 + nb, 256, 0, stream>>>(
        x, A, nvec, d_in[3], Wt, d_in[4], d_in[5], d_in[6],
        asF, adF, bF, batch, node0, rootb, flag2, N, flagv, nbx8);

    // layer-0 GEMM fused with the (atomic-free) mark2 edge scan
    k_gemm0_mark<<<nbE + gemmBlocks, 256, 0, stream>>>(
        A, Wt, B, asad, asF, adF, N, ei, rootb, flag2, E, nbE);

    // flag1 = flag2 ∪ srcs(flag2)
    k_mark1<<<nbE + nb, 256, 0, stream>>>(ei, flag2, flag1, E, N, nbE);

    // histogram with atomics ONLY for flag1 dsts (~1/3 of E)
    k_hist_masked<<<nbE, 256, 0, stream>>>(ei, flag1, counts, rank, E);

    k_scan1<<<nb, 256, 0, stream>>>(counts, offs, bsums, N);
    k_scan2<<<1, 512, 0, stream>>>(bsums, nb);

    // masked XCD-partitioned scatter (compact adj: only flag1 lists exist)
    k_scatter8<<<8 * nbE, 256, 0, stream>>>(ei, offs, bsums, rank, flag1, adj, E, N);

    // agg grid: 2 nodes per wave, 4 waves per block
    int nwaves = (N + 1) / 2;
    int aggblocks = (nwaves + 3) / 4;

    // layer 0 agg: only where layer-1 projection is needed (flag1)
    k_gat_agg<<<aggblocks, 256, 0, stream>>>(
        (const uint2*)B, asad, offs, bsums, counts, adj, bF, (uint2*)A, pE, N, 1, flag1);

    // layer 1: gemm on flag1 rows, agg only where layer-2 projection is needed (flag2)
    k_gemm_mfma<<<gemmBlocks, 256, 0, stream>>>(
        A, Wt + 16384, B, asad, asF + 128, adF + 128, N, flag1);
    k_gat_agg<<<aggblocks, 256, 0, stream>>>(
        (const uint2*)B, asad, offs, bsums, counts, adj, bF + 128, (uint2*)A, pE, N, 1, flag2);

    // layer 2: gemm on flag2 rows; final aggregation (roots) fused into heads.
    k_gemm_mfma<<<gemmBlocks, 256, 0, stream>>>(
        A, Wt + 2 * 16384, B, asad, asF + 256, adF + 256, N, flag2);

    k_heads2<<<64, 256, 0, stream>>>(
        (const unsigned*)B, asad, offs, bsums, counts, adj, bF + 256, node0, x,
        d_in[7], d_in[8], d_in[9], d_in[10], d_in[11], d_in[12],
        d_in[13], d_in[14], d_in[15], d_in[16],
        d_in[17], d_in[18], d_in[19], d_in[20],
        d_in[21], d_in[22], d_in[23], d_in[24],
        d_in[25], d_in[26], d_in[27], d_in[28],
        d_out, flagv);
}

// Round 5
// 346.407 us; speedup vs baseline: 1.6896x; 1.1801x over previous
//
#include <hip/hip_runtime.h>
#include <hip/hip_bf16.h>

typedef __hip_bfloat16 bf16;
typedef __attribute__((ext_vector_type(8))) short short8;
typedef __attribute__((ext_vector_type(4))) float floatx4;

__device__ __forceinline__ float b2f(bf16 v) { return __bfloat162float(v); }
__device__ __forceinline__ float us2f(unsigned short u) {
    return __uint_as_float(((unsigned)u) << 16);
}
__device__ __forceinline__ unsigned short f2us(float f) {
    bf16 h = __float2bfloat16(f);
    return *(unsigned short*)&h;
}
__device__ __forceinline__ float lo2f(unsigned hv) { return __uint_as_float(hv << 16); }
__device__ __forceinline__ float hi2f(unsigned hv) { return __uint_as_float(hv & 0xffff0000u); }
__device__ __forceinline__ float leaky(float v) { return v > 0.f ? v : 0.2f * v; }

__device__ __forceinline__ float ldw(const void* p, size_t i, int f32) {
    return f32 ? ((const float*)p)[i] : b2f(((const bf16*)p)[i]);
}

template <int F32>
__device__ __forceinline__ float LDWt(const void* p, size_t i) {
    return F32 ? ((const float*)p)[i] : b2f(((const bf16*)p)[i]);
}

__device__ __forceinline__ int or16(const int* f) {
    int r = 0;
#pragma unroll
    for (int j = 0; j < 16; j++) r |= f[j];
    return r;
}

__device__ __forceinline__ float wsum64(float v) {
#pragma unroll
    for (int m = 1; m <= 32; m <<= 1) v += __shfl_xor(v, m);
    return v;
}

// ---------------- dtype detection + workspace zeroing ----------------
__global__ void k_detect_zero(const void* x, int* flagv, char* zbase, size_t zbytes) {
    int b = blockIdx.x;
    int t = threadIdx.x;
    if (b < 16) {
        __shared__ int sbad;
        if (t == 0) sbad = 0;
        __syncthreads();
        float v = b2f(((const bf16*)x)[b * 256 + t]);
        if (!(fabsf(v) < 1e10f)) sbad = 1;  // benign same-value race
        __syncthreads();
        if (t == 0) flagv[b] = sbad;
    } else {
        size_t off = (size_t)(b - 16) * 4096 + (size_t)t * 16;
        if (off < zbytes) *(uint4*)(zbase + off) = make_uint4(0u, 0u, 0u, 0u);
    }
}

// ---------------- fused prep ----------------
__global__ void k_prep_fused(const void* __restrict__ x, unsigned short* __restrict__ Ab,
                             int nvec,
                             const void* __restrict__ gw, unsigned short* __restrict__ Wt,
                             const void* as_, const void* ad_, const void* b_,
                             float* asF, float* adF, float* bF,
                             const int* __restrict__ batch, int* __restrict__ node0,
                             unsigned char* __restrict__ rootb,
                             unsigned char* __restrict__ flag2, int N,
                             const int* __restrict__ flagv, int nbx8) {
    int b = blockIdx.x;
    int t = threadIdx.x;
    int f32 = or16(flagv);
    if (b < nbx8) {
        int i = b * 256 + t;
        if (i < nvec) {
            if (!f32) {
                ((uint4*)Ab)[i] = ((const uint4*)x)[i];
            } else {
                float4 a = ((const float4*)x)[2 * i];
                float4 c = ((const float4*)x)[2 * i + 1];
                uint4 o;
                o.x = ((unsigned)f2us(a.y) << 16) | f2us(a.x);
                o.y = ((unsigned)f2us(a.w) << 16) | f2us(a.z);
                o.z = ((unsigned)f2us(c.y) << 16) | f2us(c.x);
                o.w = ((unsigned)f2us(c.w) << 16) | f2us(c.z);
                ((uint4*)Ab)[i] = o;
            }
        }
    } else if (b < nbx8 + 192) {
        int i = (b - nbx8) * 256 + t;  // exactly 3*16384
        int l = i >> 14, rem = i & 16383, n = rem >> 7, k = rem & 127;
        Wt[i] = f2us(ldw(gw, (size_t)l * 16384 + (size_t)k * 128 + n, f32));
    } else if (b < nbx8 + 194) {
        int i = (b - nbx8 - 192) * 256 + t;
        if (i < 384) {
            asF[i] = ldw(as_, i, f32);
            adF[i] = ldw(ad_, i, f32);
            bF[i] = ldw(b_, i, f32);
        }
    } else {
        int i = (b - nbx8 - 194) * 256 + t;
        if (i < N) {
            int bb = batch[i];
            if (i == 0 || batch[i - 1] != bb) {
                node0[bb] = i;
                rootb[i] = 1;
                flag2[i] = 1;
            }
        }
    }
}

// ---------------- triple prefix scan: counts, flag1, flag2 ----------------
// bsums layout: int[3][512].  wp1/wp2 = exclusive positions for worklists.
__global__ void k_scan3x(const int* __restrict__ counts,
                         const unsigned char* __restrict__ flag1,
                         const unsigned char* __restrict__ flag2,
                         int* __restrict__ offs, int* __restrict__ wp1, int* __restrict__ wp2,
                         int* __restrict__ bsums, int n) {
    __shared__ int s[256];
    int tid = threadIdx.x;
    int i = blockIdx.x * 256 + tid;
#pragma unroll
    for (int a = 0; a < 3; a++) {
        int v = 0;
        if (i < n) v = (a == 0) ? counts[i] : (a == 1) ? (int)flag1[i] : (int)flag2[i];
        s[tid] = v;
        __syncthreads();
        for (int d = 1; d < 256; d <<= 1) {
            int t2 = (tid >= d) ? s[tid - d] : 0;
            __syncthreads();
            s[tid] += t2;
            __syncthreads();
        }
        int incl = s[tid];
        if (i < n) {
            if (a == 0) offs[i] = incl - v;
            else if (a == 1) wp1[i] = incl - v;
            else wp2[i] = incl - v;
        }
        if (tid == 255) bsums[a * 512 + blockIdx.x] = incl;
        __syncthreads();
    }
}

// scan the three block-sum arrays; emit nact[0]=|flag1|, nact[1]=|flag2|
__global__ void k_scan2x(int* __restrict__ bsums, int nb, int* __restrict__ nact) {
    __shared__ int s[512];
    int tid = threadIdx.x;
#pragma unroll
    for (int a = 0; a < 3; a++) {
        int* arr = bsums + a * 512;
        int v = (tid < nb) ? arr[tid] : 0;
        s[tid] = v;
        __syncthreads();
        for (int d = 1; d < 512; d <<= 1) {
            int t2 = (tid >= d) ? s[tid - d] : 0;
            __syncthreads();
            s[tid] += t2;
            __syncthreads();
        }
        arr[tid] = s[tid] - v;
        if (a >= 1 && tid == 511) nact[a - 1] = s[511];
        __syncthreads();
    }
}

// ---------------- frontier mark 1: flag1 = flag2 ∪ srcs(flag2) ----------------
__global__ void k_mark1(const int* __restrict__ ei, const unsigned char* __restrict__ flag2,
                        unsigned char* __restrict__ flag1, int E, int N, int eBlocks) {
    int b = blockIdx.x;
    if (b < eBlocks) {
        int e = b * 256 + threadIdx.x;
        if (e < E && flag2[ei[E + e]]) flag1[ei[e]] = 1;
    } else {
        int i = (b - eBlocks) * 256 + threadIdx.x;
        if (i < N && flag2[i]) flag1[i] = 1;
    }
}

// ---------------- masked histogram (atomics only for flag1 dsts, ~1/3 of E) ----
__global__ void k_hist_masked(const int* __restrict__ ei, const unsigned char* __restrict__ flag1,
                              int* __restrict__ counts, int* __restrict__ rank, int E) {
    int e = blockIdx.x * blockDim.x + threadIdx.x;
    if (e < E) {
        int d = ei[E + e];
        if (flag1[d]) rank[e] = atomicAdd(&counts[d], 1);
    }
}

// ---------------- masked XCD scatter + worklist build ----------------
__global__ void k_scatter_wl(const int* __restrict__ ei, const int* __restrict__ offs,
                             const int* __restrict__ bsums, const int* __restrict__ rank,
                             const unsigned char* __restrict__ flag1,
                             const unsigned char* __restrict__ flag2,
                             const int* __restrict__ wp1, const int* __restrict__ wp2,
                             int* __restrict__ adj, int* __restrict__ wl1, int* __restrict__ wl2,
                             int E, int N, int sBlocks) {
    int b = blockIdx.x;
    if (b < sBlocks) {
        int xcd = b & 7;
        int e = (b >> 3) * 256 + threadIdx.x;
        if (e >= E) return;
        int d = ei[E + e];
        if (!flag1[d]) return;
        int lo = (int)(((long long)N * xcd) >> 3);
        int hi = (int)(((long long)N * (xcd + 1)) >> 3);
        if (d >= lo && d < hi) adj[offs[d] + bsums[d >> 8] + rank[e]] = ei[e];
    } else {
        int i = (b - sBlocks) * 256 + threadIdx.x;
        if (i < N) {
            if (flag1[i]) wl1[wp1[i] + bsums[512 + (i >> 8)]] = i;
            if (flag2[i]) wl2[wp2[i] + bsums[1024 + (i >> 8)]] = i;
        }
    }
}

// ---------------- MFMA GEMM body: LDS-staged Wt + fused attention scalars ----
// wl (optional): gather mode — block bb covers worklist rows [bb*64, bb*64+64);
// nactp = device count.  Wt staged into Ws[128][136] (pad -> 2-way banks, free).
__device__ __forceinline__ void gemm_body(
    const unsigned short* __restrict__ Ab, const unsigned short* __restrict__ Wt,
    unsigned short* __restrict__ Bb, float4* __restrict__ asadv,
    const float* __restrict__ asF, const float* __restrict__ adF, int N,
    const int* __restrict__ wl, const int* __restrict__ nactp, int bb) {
    __shared__ __align__(16) unsigned short Ws[128 * 136];
    __shared__ __align__(16) unsigned short Cs[64 * 136];

    int t = threadIdx.x;
    int r0 = bb * 64;
    int nact = wl ? *nactp : N;
    if (r0 >= nact) return;  // uniform per block

    // ---- stage Wt (32 KB) into LDS: 8 x uint4 per thread ----
    {
        const uint4* src = (const uint4*)Wt;  // 2048 uint4
#pragma unroll
        for (int k = 0; k < 8; k++) {
            int j = t + k * 256;
            int row = j >> 4, c16 = j & 15;
            *(uint4*)&Ws[row * 136 + c16 * 8] = src[j];
        }
    }
    __syncthreads();

    int lane = t & 63;
    int w = t >> 6;
    int ln = lane & 15;
    int quad = lane >> 4;

    int idx = r0 + w * 16 + ln;
    bool valid = idx < nact;
    int arow = idx < N ? idx : N - 1;
    if (wl) arow = valid ? wl[idx] : 0;
    bool wave_active = __any((int)valid);

    if (wave_active) {
        const unsigned short* ap = Ab + (size_t)arow * 128 + quad * 8;

        short8 afrag[4];
        if (valid) {
#pragma unroll
            for (int kt = 0; kt < 4; kt++)
                afrag[kt] = *(const short8*)(ap + kt * 32);
        } else {
#pragma unroll
            for (int kt = 0; kt < 4; kt++)
                afrag[kt] = (short8){0, 0, 0, 0, 0, 0, 0, 0};
        }

        floatx4 acc[8];
#pragma unroll
        for (int nt = 0; nt < 8; nt++) acc[nt] = (floatx4){0.f, 0.f, 0.f, 0.f};

#pragma unroll
        for (int nt = 0; nt < 8; nt++) {
            const unsigned short* wp = Ws + (nt * 16 + ln) * 136 + quad * 8;
#pragma unroll
            for (int kt = 0; kt < 4; kt++) {
                short8 bfrag = *(const short8*)(wp + kt * 32);
                acc[nt] = __builtin_amdgcn_mfma_f32_16x16x32_bf16(afrag[kt], bfrag, acc[nt], 0, 0, 0);
            }
        }

        float as0[4] = {0, 0, 0, 0}, as1[4] = {0, 0, 0, 0};
        float ad0[4] = {0, 0, 0, 0}, ad1[4] = {0, 0, 0, 0};
#pragma unroll
        for (int nt = 0; nt < 8; nt++) {
            float asc = asF[nt * 16 + ln];
            float adc = adF[nt * 16 + ln];
#pragma unroll
            for (int r = 0; r < 4; r++) {
                float v = acc[nt][r];
                Cs[(w * 16 + quad * 4 + r) * 136 + nt * 16 + ln] = f2us(v);
                if (nt < 4) { as0[r] += v * asc; ad0[r] += v * adc; }
                else        { as1[r] += v * asc; ad1[r] += v * adc; }
            }
        }
#pragma unroll
        for (int mask = 1; mask <= 8; mask <<= 1) {
#pragma unroll
            for (int r = 0; r < 4; r++) {
                as0[r] += __shfl_xor(as0[r], mask);
                as1[r] += __shfl_xor(as1[r], mask);
                ad0[r] += __shfl_xor(ad0[r], mask);
                ad1[r] += __shfl_xor(ad1[r], mask);
            }
        }
        if (ln == 0) {
#pragma unroll
            for (int r = 0; r < 4; r++) {
                int idx3 = r0 + w * 16 + quad * 4 + r;
                if (idx3 < nact) {
                    int row = wl ? wl[idx3] : idx3;
                    asadv[row] = make_float4(as0[r], as1[r], ad0[r], ad1[r]);
                }
            }
        }
    }
    __syncthreads();

    {
        int idx2 = r0 + (t >> 2);
        int cseg = (t & 3) * 32;
        if (idx2 < nact) {
            int grow = wl ? wl[idx2] : idx2;
            const short8* srcp = (const short8*)&Cs[(t >> 2) * 136 + cseg];
            short8* dstp = (short8*)&Bb[(size_t)grow * 128 + cseg];
#pragma unroll
            for (int u = 0; u < 4; u++) dstp[u] = srcp[u];
        }
    }
}

// layers 1,2: gather GEMM over a worklist
__global__ __launch_bounds__(256) void k_gemm_mfma(
    const unsigned short* __restrict__ Ab, const unsigned short* __restrict__ Wt,
    unsigned short* __restrict__ Bb, float4* __restrict__ asadv,
    const float* __restrict__ asF, const float* __restrict__ adF, int N,
    const int* __restrict__ wl, const int* __restrict__ nactp) {
    gemm_body(Ab, Wt, Bb, asadv, asF, adF, N, wl, nactp, blockIdx.x);
}

// layer 0: full GEMM fused with the (atomic-free) mark2 edge scan
__global__ __launch_bounds__(256) void k_gemm0_mark(
    const unsigned short* __restrict__ Ab, const unsigned short* __restrict__ Wt,
    unsigned short* __restrict__ Bb, float4* __restrict__ asadv,
    const float* __restrict__ asF, const float* __restrict__ adF, int N,
    const int* __restrict__ ei, const unsigned char* __restrict__ rootb,
    unsigned char* __restrict__ flag2, int E, int markBlocks) {
    int b = blockIdx.x;
    if (b < markBlocks) {
        int e = b * 256 + threadIdx.x;
        if (e < E) {
            int d = ei[E + e];
            if (rootb[d]) flag2[ei[e]] = 1;
        }
        return;
    }
    gemm_body(Ab, Wt, Bb, asadv, asF, adF, N, nullptr, nullptr, b - markBlocks);
}

// ---------------- GAT aggregation over a compact worklist ----------------
__global__ void k_gat_agg(const uint2* __restrict__ Bu2, const float4* __restrict__ asadv,
                          const int* __restrict__ offs, const int* __restrict__ bsums,
                          const int* __restrict__ counts,
                          const int* __restrict__ adj, const float* __restrict__ biasF,
                          uint2* __restrict__ Au2, float2* __restrict__ pE,
                          const int* __restrict__ nactp, int dorelu,
                          const int* __restrict__ wl) {
    int wave = (blockIdx.x * blockDim.x + threadIdx.x) >> 6;
    int lane = threadIdx.x & 63;
    int hl = lane & 31;          // lane within node-half
    int hb = lane & 32;          // shfl broadcast base for this half
    int idx = wave * 2 + (lane >> 5);
    if (idx >= *nactp) return;   // half-wave exits; shfls stay in-half
    int node = wl[idx];
    int head = hl >> 4;

    float4 self = asadv[node];
    float ad0 = self.z, ad1 = self.w;
    float es0 = __expf(leaky(self.x + ad0));
    float es1 = __expf(leaky(self.y + ad1));

    int o = offs[node] + bsums[node >> 8];
    int c = counts[node];
    uint2 hvs = Bu2[(size_t)node * 32 + hl];
    float acc0, acc1, acc2, acc3;

    if (c <= 32) {
        // ---- fast path ----
        int src_r = 0;
        float p0 = 0.f, p1 = 0.f;
        if (hl < c) {
            src_r = adj[o + hl];
            float4 av = asadv[src_r];
            p0 = __expf(leaky(av.x + ad0));
            p1 = __expf(leaky(av.y + ad1));
        }
        float t0 = p0, t1 = p1;
#pragma unroll
        for (int mask = 1; mask <= 16; mask <<= 1) {
            t0 += __shfl_xor(t0, mask);
            t1 += __shfl_xor(t1, mask);
        }
        float inv0 = 1.f / (es0 + t0 + 1e-16f);
        float inv1 = 1.f / (es1 + t1 + 1e-16f);
        p0 *= inv0;
        p1 *= inv1;
        float aself = head ? es1 * inv1 : es0 * inv0;
        acc0 = aself * lo2f(hvs.x);
        acc1 = aself * hi2f(hvs.x);
        acc2 = aself * lo2f(hvs.y);
        acc3 = aself * hi2f(hvs.y);

        uint2 hq[4];
#pragma unroll
        for (int j = 0; j < 4; j++) {
            int s2 = __shfl(src_r, hb + j);
            hq[j] = make_uint2(0u, 0u);
            if (j < c) hq[j] = Bu2[(size_t)s2 * 32 + hl];
        }

        for (int base = 0; base < c; base += 4) {
            uint2 cur[4];
            float av4[4];
#pragma unroll
            for (int j = 0; j < 4; j++) {
                cur[j] = hq[j];
                int idx2 = (base + j) & 31;
                float a0 = __shfl(p0, hb + idx2);
                float a1 = __shfl(p1, hb + idx2);
                float a = head ? a1 : a0;
                av4[j] = (base + j < c) ? a : 0.f;
            }
#pragma unroll
            for (int j = 0; j < 4; j++) {
                int nx = base + 4 + j;
                int s2 = __shfl(src_r, hb + (nx & 31));
                if (nx < c) hq[j] = Bu2[(size_t)s2 * 32 + hl];
            }
#pragma unroll
            for (int j = 0; j < 4; j++) {
                acc0 += av4[j] * lo2f(cur[j].x);
                acc1 += av4[j] * hi2f(cur[j].x);
                acc2 += av4[j] * lo2f(cur[j].y);
                acc3 += av4[j] * hi2f(cur[j].y);
            }
        }
    } else {
        // ---- slow path (rare, c>32) ----
        float sum0 = es0, sum1 = es1;
        for (int base = 0; base < c; base += 32) {
            int i = base + hl;
            float p0 = 0.f, p1 = 0.f;
            if (i < c) {
                int s = adj[o + i];
                float4 av = asadv[s];
                p0 = __expf(leaky(av.x + ad0));
                p1 = __expf(leaky(av.y + ad1));
                pE[o + i] = make_float2(p0, p1);
            }
            float t0 = p0, t1 = p1;
#pragma unroll
            for (int mask = 1; mask <= 16; mask <<= 1) {
                t0 += __shfl_xor(t0, mask);
                t1 += __shfl_xor(t1, mask);
            }
            sum0 += t0; sum1 += t1;
        }
        float inv0 = 1.f / (sum0 + 1e-16f);
        float inv1 = 1.f / (sum1 + 1e-16f);
        float aself = head ? es1 * inv1 : es0 * inv0;
        float invh = head ? inv1 : inv0;
        acc0 = aself * lo2f(hvs.x);
        acc1 = aself * hi2f(hvs.x);
        acc2 = aself * lo2f(hvs.y);
        acc3 = aself * hi2f(hvs.y);
        for (int i = 0; i < c; i++) {
            int s = adj[o + i];
            float2 pp = pE[o + i];
            uint2 hv = Bu2[(size_t)s * 32 + hl];
            float a = (head ? pp.y : pp.x) * invh;
            acc0 += a * lo2f(hv.x);
            acc1 += a * hi2f(hv.x);
            acc2 += a * lo2f(hv.y);
            acc3 += a * hi2f(hv.y);
        }
    }

    float4 bb4 = ((const float4*)biasF)[hl];
    float q0 = acc0 + bb4.x;
    float q1 = acc1 + bb4.y;
    float q2 = acc2 + bb4.z;
    float q3 = acc3 + bb4.w;
    if (dorelu) {
        q0 = fmaxf(q0, 0.f); q1 = fmaxf(q1, 0.f);
        q2 = fmaxf(q2, 0.f); q3 = fmaxf(q3, 0.f);
    }
    Au2[(size_t)node * 32 + hl] =
        make_uint2(((unsigned)f2us(q1) << 16) | f2us(q0),
                   ((unsigned)f2us(q3) << 16) | f2us(q2));
}

// ---------------- heads: ONE WAVE per graph (fused root aggregation) ----------
// All __shfl broadcasts run with FULL exec (compute-both-then-select).
template <int F32>
__device__ void heads_body(
    const unsigned* __restrict__ Brow, const float4* __restrict__ asadv,
    const int* __restrict__ offs, const int* __restrict__ bsums,
    const int* __restrict__ counts, const int* __restrict__ adj,
    const float* __restrict__ biasF, const int* __restrict__ node0,
    const void* __restrict__ x,
    const void* sW, const void* sb,
    const void* pW1, const void* pb1, const void* pW2, const void* pb2,
    const void* cW1, const void* cb1, const void* cW2, const void* cb2,
    const void* fW1, const void* fb1, const void* fW2, const void* fb2,
    const void* bW1, const void* bb1, const void* bW2, const void* bb2,
    const void* zW1, const void* zb1, const void* zW2, const void* zb2,
    void* __restrict__ outv) {
    int lane = threadIdx.x & 63;
    int g = blockIdx.x * 4 + (threadIdx.x >> 6);
    bf16* outb = (bf16*)outv;
    float* outf = (float*)outv;
#define STORE(idx, val) do { if (F32) outf[idx] = (val); else outb[idx] = __float2bfloat16(val); } while (0)

    int n0 = node0[g];

    float4 self = asadv[n0];
    float es0 = __expf(leaky(self.x + self.z));
    float es1 = __expf(leaky(self.y + self.w));
    int o = offs[n0] + bsums[n0 >> 8];
    int c = counts[n0];

    int srcl = 0;
    float p0 = 0.f, p1 = 0.f;
    if (lane < c) {
        srcl = adj[o + lane];
        float4 av = asadv[srcl];
        p0 = __expf(leaky(av.x + self.z));
        p1 = __expf(leaky(av.y + self.w));
    }
    float sum0 = es0 + wsum64(p0);
    float sum1 = es1 + wsum64(p1);
    for (int base = 64; base < c; base += 64) {
        float q0 = 0.f, q1 = 0.f;
        if (base + lane < c) {
            int s = adj[o + base + lane];
            float4 av = asadv[s];
            q0 = __expf(leaky(av.x + self.z));
            q1 = __expf(leaky(av.y + self.w));
        }
        sum0 += wsum64(q0);
        sum1 += wsum64(q1);
    }
    float inv0 = 1.f / (sum0 + 1e-16f);
    float inv1 = 1.f / (sum1 + 1e-16f);
    float invh = (lane < 32) ? inv0 : inv1;

    unsigned hv0 = Brow[(size_t)n0 * 64 + lane];
    float aself = ((lane < 32) ? es0 : es1) * invh;
    float h0 = aself * lo2f(hv0);
    float h1 = aself * hi2f(hv0);
    int cc = min(c, 64);
    for (int j = 0; j < cc; ++j) {
        int s = __shfl(srcl, j);
        float a0 = __shfl(p0, j);
        float a1 = __shfl(p1, j);
        float aa = ((lane < 32) ? a0 : a1) * invh;
        unsigned hv = Brow[(size_t)s * 64 + lane];
        h0 += aa * lo2f(hv);
        h1 += aa * hi2f(hv);
    }
    for (int j = 64; j < c; ++j) {
        int s = adj[o + j];
        float4 av = asadv[s];
        float aa = (lane < 32) ? __expf(leaky(av.x + self.z)) * inv0
                               : __expf(leaky(av.y + self.w)) * inv1;
        unsigned hv = Brow[(size_t)s * 64 + lane];
        h0 += aa * lo2f(hv);
        h1 += aa * hi2f(hv);
    }
    float2 bias2 = ((const float2*)biasF)[lane];
    h0 += bias2.x;
    h1 += bias2.y;

    float rD = (lane < 22) ? LDWt<F32>(x, (size_t)n0 * 128 + lane) : 0.f;

    float p = 0.f;
    for (int i = 0; i < 64; ++i) {
        p += __shfl(h0, i) * LDWt<F32>(sW, (size_t)(2 * i) * 64 + lane);
        p += __shfl(h1, i) * LDWt<F32>(sW, (size_t)(2 * i + 1) * 64 + lane);
    }
    for (int i = 0; i < 22; ++i)
        p += __shfl(rD, i) * LDWt<F32>(sW, (size_t)(128 + i) * 64 + lane);
    float zf = fmaxf(p + LDWt<F32>(sb, lane), 0.f);

    float bin1 = (lane < 22) ? rD : 0.f;

#pragma unroll
    for (int k = 0; k < 3; ++k) {
        float pp = 0.f;
        for (int i = 0; i < 64; ++i)
            pp += __shfl(zf, i) * LDWt<F32>(pW1, (size_t)k * 4096 + (size_t)i * 64 + lane);
        float tt = fmaxf(pp + LDWt<F32>(pb1, k * 64 + lane), 0.f);
#pragma unroll
        for (int o2 = 0; o2 < 3; ++o2) {
            float v = wsum64(tt * LDWt<F32>(pW2, (size_t)k * 192 + (size_t)lane * 3 + o2));
            if (lane == 0) STORE(k * 768 + g * 3 + o2, v + LDWt<F32>(pb2, k * 3 + o2));
        }
    }

    {
        float pp = 0.f;
        for (int i = 0; i < 64; ++i)
            pp += __shfl(zf, i) * LDWt<F32>(cW1, (size_t)i * 64 + lane);
        float tt = fmaxf(pp + LDWt<F32>(cb1, lane), 0.f);
#pragma unroll
        for (int o2 = 0; o2 < 5; ++o2) {
            float v = wsum64(tt * LDWt<F32>(cW2, (size_t)lane * 5 + o2)) + LDWt<F32>(cb2, o2);
            bin1 = (lane == 22 + o2) ? v : bin1;
            if (lane == 0) STORE(2304 + g * 5 + o2, v);
        }
    }

#pragma unroll
    for (int k = 0; k < 2; ++k) {
        float pp = 0.f;
        for (int i = 0; i < 64; ++i)
            pp += __shfl(zf, i) * LDWt<F32>(fW1, (size_t)k * 4096 + (size_t)i * 64 + lane);
        float tt = fmaxf(pp + LDWt<F32>(fb1, k * 64 + lane), 0.f);
        float v = wsum64(tt * LDWt<F32>(fW2, k * 64 + lane)) + LDWt<F32>(fb2, k);
        bin1 = (lane == 27 + k) ? v : bin1;
        if (lane == 0) STORE(3584 + k * 256 + g, v);
    }

    {
        float pp = 0.f;
        for (int i = 0; i < 64; ++i)
            pp += __shfl(zf, i) * LDWt<F32>(bW1, (size_t)i * 64 + lane);
        for (int i = 0; i < 29; ++i)
            pp += __shfl(bin1, i) * LDWt<F32>(bW1, (size_t)(64 + i) * 64 + lane);
        float tt = fmaxf(pp + LDWt<F32>(bb1, lane), 0.f);
        float v = wsum64(tt * LDWt<F32>(bW2, lane)) + LDWt<F32>(bb2, 0);
        bin1 = (lane == 29) ? v : bin1;
        if (lane == 0) STORE(4096 + g, v);
    }

    {
        float pp = 0.f;
        for (int i = 0; i < 64; ++i)
            pp += __shfl(zf, i) * LDWt<F32>(zW1, (size_t)i * 64 + lane);
        for (int i = 0; i < 30; ++i)
            pp += __shfl(bin1, i) * LDWt<F32>(zW1, (size_t)(64 + i) * 64 + lane);
        float tt = fmaxf(pp + LDWt<F32>(zb1, lane), 0.f);
#pragma unroll
        for (int o2 = 0; o2 < 8; ++o2) {
            float v = wsum64(tt * LDWt<F32>(zW2, (size_t)lane * 8 + o2));
            if (lane == 0) STORE(4352 + g * 8 + o2, v + LDWt<F32>(zb2, o2));
        }
    }
#undef STORE
}

__global__ __launch_bounds__(256) void k_heads2(
    const unsigned* __restrict__ Brow, const float4* __restrict__ asadv,
    const int* __restrict__ offs, const int* __restrict__ bsums,
    const int* __restrict__ counts, const int* __restrict__ adj,
    const float* __restrict__ biasF, const int* __restrict__ node0,
    const void* __restrict__ x,
    const void* sW, const void* sb,
    const void* pW1, const void* pb1, const void* pW2, const void* pb2,
    const void* cW1, const void* cb1, const void* cW2, const void* cb2,
    const void* fW1, const void* fb1, const void* fW2, const void* fb2,
    const void* bW1, const void* bb1, const void* bW2, const void* bb2,
    const void* zW1, const void* zb1, const void* zW2, const void* zb2,
    void* __restrict__ outv, const int* __restrict__ flagv) {
    if (or16(flagv))
        heads_body<1>(Brow, asadv, offs, bsums, counts, adj, biasF, node0, x,
                      sW, sb, pW1, pb1, pW2, pb2, cW1, cb1, cW2, cb2,
                      fW1, fb1, fW2, fb2, bW1, bb1, bW2, bb2,
                      zW1, zb1, zW2, zb2, outv);
    else
        heads_body<0>(Brow, asadv, offs, bsums, counts, adj, biasF, node0, x,
                      sW, sb, pW1, pb1, pW2, pb2, cW1, cb1, cW2, cb2,
                      fW1, fb1, fW2, fb2, bW1, bb1, bW2, bb2,
                      zW1, zb1, zW2, zb2, outv);
}

// ---------------- host ----------------

extern "C" void kernel_launch(void* const* d_in, const int* in_sizes, int n_in,
                              void* d_out, int out_size, void* d_ws, size_t ws_size,
                              hipStream_t stream) {
    const void* x     = d_in[0];
    const int*  ei    = (const int*)d_in[1];
    const int*  batch = (const int*)d_in[2];

    int N = in_sizes[0] / 128;
    int E = in_sizes[1] / 2;

    char* w = (char*)d_ws;
    float4* asad = (float4*)w;              w += (size_t)N * 16;
    unsigned short* A = (unsigned short*)w; w += (size_t)N * 128 * 2;
    unsigned short* B = (unsigned short*)w; w += (size_t)N * 128 * 2;
    float2* pE = (float2*)w;                w += (size_t)E * 8;
    unsigned short* Wt = (unsigned short*)w; w += 3 * 16384 * 2;
    float* asF = (float*)w;                 w += 384 * 4;
    float* adF = (float*)w;                 w += 384 * 4;
    float* bF = (float*)w;                  w += 384 * 4;
    int* offs = (int*)w;                    w += (size_t)N * 4;
    int* wp1 = (int*)w;                     w += (size_t)N * 4;
    int* wp2 = (int*)w;                     w += (size_t)N * 4;
    int* wl1 = (int*)w;                     w += (size_t)N * 4;
    int* wl2 = (int*)w;                     w += (size_t)N * 4;
    int* rank = (int*)w;                    w += (size_t)E * 4;
    int* adj = (int*)w;                     w += (size_t)E * 4;
    int* bsums = (int*)w;                   w += 3 * 512 * 4;
    int* node0 = (int*)w;                   w += 256 * 4;
    int* nact = (int*)w;                    w += 64;
    // ---- contiguous zero-region (zeroed by k_detect_zero) ----
    char* zbase = w;
    int* counts = (int*)w;                  w += (size_t)N * 4;
    unsigned char* flag1 = (unsigned char*)w; w += (size_t)N;
    unsigned char* flag2 = (unsigned char*)w; w += (size_t)N;
    unsigned char* rootb = (unsigned char*)w; w += (size_t)N;
    size_t zbytes = (size_t)N * 7;
    int* flagv = (int*)w;                   w += 64;

    int nb = (N + 255) / 256;
    int nvec = N * 16;
    int nbx8 = (nvec + 255) / 256;
    int nbE = (E + 255) / 256;
    int gemmBlocks = (N + 63) / 64;
    int zBlocks = (int)((zbytes + 4095) / 4096);

    k_detect_zero<<<16 + zBlocks, 256, 0, stream>>>(x, flagv, zbase, zbytes);

    k_prep_fused<<<nbx8 + 194 + nb, 256, 0, stream>>>(
        x, A, nvec, d_in[3], Wt, d_in[4], d_in[5], d_in[6],
        asF, adF, bF, batch, node0, rootb, flag2, N, flagv, nbx8);

    // layer-0 GEMM (LDS-staged Wt) fused with the mark2 edge scan
    k_gemm0_mark<<<nbE + gemmBlocks, 256, 0, stream>>>(
        A, Wt, B, asad, asF, adF, N, ei, rootb, flag2, E, nbE);

    // flag1 = flag2 ∪ srcs(flag2)
    k_mark1<<<nbE + nb, 256, 0, stream>>>(ei, flag2, flag1, E, N, nbE);

    // histogram with atomics only for flag1 dsts
    k_hist_masked<<<nbE, 256, 0, stream>>>(ei, flag1, counts, rank, E);

    // triple scan: counts -> offs, flag1 -> wp1, flag2 -> wp2
    k_scan3x<<<nb, 256, 0, stream>>>(counts, flag1, flag2, offs, wp1, wp2, bsums, N);
    k_scan2x<<<1, 512, 0, stream>>>(bsums, nb, nact);

    // masked XCD scatter + worklist build
    int sBlocks = 8 * nbE;
    k_scatter_wl<<<sBlocks + nb, 256, 0, stream>>>(
        ei, offs, bsums, rank, flag1, flag2, wp1, wp2, adj, wl1, wl2, E, N, sBlocks);

    int nwaves = (N + 1) / 2;
    int aggblocks = (nwaves + 3) / 4;

    // layer 0 agg over wl1 (compact)
    k_gat_agg<<<aggblocks, 256, 0, stream>>>(
        (const uint2*)B, asad, offs, bsums, counts, adj, bF, (uint2*)A, pE,
        nact, 1, wl1);

    // layer 1: gather-GEMM over wl1, agg over wl2
    k_gemm_mfma<<<gemmBlocks, 256, 0, stream>>>(
        A, Wt + 16384, B, asad, asF + 128, adF + 128, N, wl1, nact);
    k_gat_agg<<<aggblocks, 256, 0, stream>>>(
        (const uint2*)B, asad, offs, bsums, counts, adj, bF + 128, (uint2*)A, pE,
        nact + 1, 1, wl2);

    // layer 2: gather-GEMM over wl2; root aggregation fused into heads
    k_gemm_mfma<<<gemmBlocks, 256, 0, stream>>>(
        A, Wt + 2 * 16384, B, asad, asF + 256, adF + 256, N, wl2, nact + 1);

    k_heads2<<<64, 256, 0, stream>>>(
        (const unsigned*)B, asad, offs, bsums, counts, adj, bF + 256, node0, x,
        d_in[7], d_in[8], d_in[9], d_in[10], d_in[11], d_in[12],
        d_in[13], d_in[14], d_in[15], d_in[16],
        d_in[17], d_in[18], d_in[19], d_in[20],
        d_in[21], d_in[22], d_in[23], d_in[24],
        d_in[25], d_in[26], d_in[27], d_in[28],
        d_out, flagv);
}

// Round 6
// 316.391 us; speedup vs baseline: 1.8499x; 1.0949x over previous
//
#include <hip/hip_runtime.h>
#include <hip/hip_bf16.h>

typedef __hip_bfloat16 bf16;
typedef __attribute__((ext_vector_type(8))) short short8;
typedef __attribute__((ext_vector_type(4))) float floatx4;

#define MF(a, b, c) __builtin_amdgcn_mfma_f32_16x16x32_bf16(a, b, c, 0, 0, 0)

__device__ __forceinline__ float b2f(bf16 v) { return __bfloat162float(v); }
__device__ __forceinline__ unsigned short f2us(float f) {
    bf16 h = __float2bfloat16(f);
    return *(unsigned short*)&h;
}
__device__ __forceinline__ float lo2f(unsigned hv) { return __uint_as_float(hv << 16); }
__device__ __forceinline__ float hi2f(unsigned hv) { return __uint_as_float(hv & 0xffff0000u); }
__device__ __forceinline__ float leaky(float v) { return v > 0.f ? v : 0.2f * v; }

__device__ __forceinline__ float ldw(const void* p, size_t i, int f32) {
    return f32 ? ((const float*)p)[i] : b2f(((const bf16*)p)[i]);
}

template <int F32>
__device__ __forceinline__ float LDWt(const void* p, size_t i) {
    return F32 ? ((const float*)p)[i] : b2f(((const bf16*)p)[i]);
}

__device__ __forceinline__ int or16(const int* f) {
    int r = 0;
#pragma unroll
    for (int j = 0; j < 16; j++) r |= f[j];
    return r;
}

// reduce part[0..3] over the 16 lanes of a quad-group (masks 1,2,4,8)
__device__ __forceinline__ void quadred(float part[4]) {
#pragma unroll
    for (int m = 1; m <= 8; m <<= 1)
#pragma unroll
        for (int r = 0; r < 4; r++) part[r] += __shfl_xor(part[r], m);
}

// ---------------- dtype detection + workspace zeroing ----------------
__global__ void k_detect_zero(const void* x, int* flagv, char* zbase, size_t zbytes) {
    int b = blockIdx.x;
    int t = threadIdx.x;
    if (b < 16) {
        __shared__ int sbad;
        if (t == 0) sbad = 0;
        __syncthreads();
        float v = b2f(((const bf16*)x)[b * 256 + t]);
        if (!(fabsf(v) < 1e10f)) sbad = 1;  // benign same-value race
        __syncthreads();
        if (t == 0) flagv[b] = sbad;
    } else {
        size_t off = (size_t)(b - 16) * 4096 + (size_t)t * 16;
        if (off < zbytes) *(uint4*)(zbase + off) = make_uint4(0u, 0u, 0u, 0u);
    }
}

// ---------------- fused prep: x->bf16 (vec), Wt transpose, head-W1 transposes,
// small weights, node0/root marks ----
__global__ void k_prep_fused(const void* __restrict__ x, unsigned short* __restrict__ Ab,
                             int nvec,
                             const void* __restrict__ gw, unsigned short* __restrict__ Wt,
                             const void* as_, const void* ad_, const void* b_,
                             float* asF, float* adF, float* bF,
                             const void* sW_, const void* pW1_, const void* cW1_,
                             const void* fW1_, const void* bW1_, const void* zW1_,
                             unsigned short* __restrict__ Whd,
                             const int* __restrict__ batch, int* __restrict__ node0,
                             unsigned char* __restrict__ rootb,
                             unsigned char* __restrict__ flag2, int N,
                             const int* __restrict__ flagv, int nbx8) {
    int b = blockIdx.x;
    int t = threadIdx.x;
    int f32 = or16(flagv);
    if (b < nbx8) {
        int i = b * 256 + t;
        if (i < nvec) {
            if (!f32) {
                ((uint4*)Ab)[i] = ((const uint4*)x)[i];
            } else {
                float4 a = ((const float4*)x)[2 * i];
                float4 c = ((const float4*)x)[2 * i + 1];
                uint4 o;
                o.x = ((unsigned)f2us(a.y) << 16) | f2us(a.x);
                o.y = ((unsigned)f2us(a.w) << 16) | f2us(a.z);
                o.z = ((unsigned)f2us(c.y) << 16) | f2us(c.x);
                o.w = ((unsigned)f2us(c.w) << 16) | f2us(c.z);
                ((uint4*)Ab)[i] = o;
            }
        }
    } else if (b < nbx8 + 192) {
        int i = (b - nbx8) * 256 + t;  // exactly 3*16384
        int l = i >> 14, rem = i & 16383, n = rem >> 7, k = rem & 127;
        Wt[i] = f2us(ldw(gw, (size_t)l * 16384 + (size_t)k * 128 + n, f32));
    } else if (b < nbx8 + 194) {
        int i = (b - nbx8 - 192) * 256 + t;
        if (i < 384) {
            asF[i] = ldw(as_, i, f32);
            adF[i] = ldw(ad_, i, f32);
            bF[i] = ldw(b_, i, f32);
        }
    } else if (b < nbx8 + 194 + 184) {
        // transposed head W1s -> Whd (bf16, col-major [n][k], zero-padded K)
        // layout: sWt[64][160] @0; pW1t 3x[64][64] @10240; cW1t @22528;
        //         fW1t 2x @26624; bW1t[64][96] @34816; zW1t[64][96] @40960.
        int i = (b - nbx8 - 194) * 256 + t;  // 0..47103
        float v;
        if (i < 10240) {
            int n = i / 160, k = i - n * 160;
            v = (k < 150) ? ldw(sW_, (size_t)k * 64 + n, f32) : 0.f;
        } else if (i < 22528) {
            int j = i - 10240;
            int kk = j >> 12, r = j & 4095, n = r >> 6, k = r & 63;
            v = ldw(pW1_, (size_t)kk * 4096 + (size_t)k * 64 + n, f32);
        } else if (i < 26624) {
            int j = i - 22528;
            int n = j >> 6, k = j & 63;
            v = ldw(cW1_, (size_t)k * 64 + n, f32);
        } else if (i < 34816) {
            int j = i - 26624;
            int kk = j >> 12, r = j & 4095, n = r >> 6, k = r & 63;
            v = ldw(fW1_, (size_t)kk * 4096 + (size_t)k * 64 + n, f32);
        } else if (i < 40960) {
            int j = i - 34816;
            int n = j / 96, k = j - n * 96;
            v = (k < 93) ? ldw(bW1_, (size_t)k * 64 + n, f32) : 0.f;
        } else {
            int j = i - 40960;
            int n = j / 96, k = j - n * 96;
            v = (k < 94) ? ldw(zW1_, (size_t)k * 64 + n, f32) : 0.f;
        }
        Whd[i] = f2us(v);
    } else {
        int i = (b - nbx8 - 194 - 184) * 256 + t;
        if (i < N) {
            int bb = batch[i];
            if (i == 0 || batch[i - 1] != bb) {
                node0[bb] = i;
                rootb[i] = 1;
                flag2[i] = 1;
            }
        }
    }
}

// ---------------- triple prefix scan: counts, flag1, flag2 ----------------
__global__ void k_scan3x(const int* __restrict__ counts,
                         const unsigned char* __restrict__ flag1,
                         const unsigned char* __restrict__ flag2,
                         int* __restrict__ offs, int* __restrict__ wp1, int* __restrict__ wp2,
                         int* __restrict__ bsums, int n) {
    __shared__ int s[256];
    int tid = threadIdx.x;
    int i = blockIdx.x * 256 + tid;
#pragma unroll
    for (int a = 0; a < 3; a++) {
        int v = 0;
        if (i < n) v = (a == 0) ? counts[i] : (a == 1) ? (int)flag1[i] : (int)flag2[i];
        s[tid] = v;
        __syncthreads();
        for (int d = 1; d < 256; d <<= 1) {
            int t2 = (tid >= d) ? s[tid - d] : 0;
            __syncthreads();
            s[tid] += t2;
            __syncthreads();
        }
        int incl = s[tid];
        if (i < n) {
            if (a == 0) offs[i] = incl - v;
            else if (a == 1) wp1[i] = incl - v;
            else wp2[i] = incl - v;
        }
        if (tid == 255) bsums[a * 512 + blockIdx.x] = incl;
        __syncthreads();
    }
}

__global__ void k_scan2x(int* __restrict__ bsums, int nb, int* __restrict__ nact) {
    __shared__ int s[512];
    int tid = threadIdx.x;
#pragma unroll
    for (int a = 0; a < 3; a++) {
        int* arr = bsums + a * 512;
        int v = (tid < nb) ? arr[tid] : 0;
        s[tid] = v;
        __syncthreads();
        for (int d = 1; d < 512; d <<= 1) {
            int t2 = (tid >= d) ? s[tid - d] : 0;
            __syncthreads();
            s[tid] += t2;
            __syncthreads();
        }
        arr[tid] = s[tid] - v;
        if (a >= 1 && tid == 511) nact[a - 1] = s[511];
        __syncthreads();
    }
}

// ---------------- frontier mark 1: flag1 = flag2 ∪ srcs(flag2) ----------------
__global__ void k_mark1(const int* __restrict__ ei, const unsigned char* __restrict__ flag2,
                        unsigned char* __restrict__ flag1, int E, int N, int eBlocks) {
    int b = blockIdx.x;
    if (b < eBlocks) {
        int e = b * 256 + threadIdx.x;
        if (e < E && flag2[ei[E + e]]) flag1[ei[e]] = 1;
    } else {
        int i = (b - eBlocks) * 256 + threadIdx.x;
        if (i < N && flag2[i]) flag1[i] = 1;
    }
}

// ---------------- masked histogram: NON-RETURNING atomics (no rank) ----------
__global__ void k_hist_masked(const int* __restrict__ ei, const unsigned char* __restrict__ flag1,
                              int* __restrict__ counts, int E) {
    int e = blockIdx.x * blockDim.x + threadIdx.x;
    if (e < E) {
        int d = ei[E + e];
        if (flag1[d]) atomicAdd(&counts[d], 1);  // result unused -> no wave stall
    }
}

// ---------------- single-pass cursor scatter + worklist build ----------------
// Order within each adjacency list is nondeterministic (fp-sum reorder only).
// Replaces the 8x XCD-replicated pass: ei fetched ONCE instead of 8x.
__global__ void k_scatter_wl(const int* __restrict__ ei, const int* __restrict__ offs,
                             const int* __restrict__ bsums, int* __restrict__ cur,
                             const unsigned char* __restrict__ flag1,
                             const unsigned char* __restrict__ flag2,
                             const int* __restrict__ wp1, const int* __restrict__ wp2,
                             int* __restrict__ adj, int* __restrict__ wl1, int* __restrict__ wl2,
                             int E, int N, int eBlocks) {
    int b = blockIdx.x;
    if (b < eBlocks) {
        int e = b * 256 + threadIdx.x;
        if (e >= E) return;
        int d = ei[E + e];
        if (!flag1[d]) return;
        int r = atomicAdd(&cur[d], 1);
        adj[offs[d] + bsums[d >> 8] + r] = ei[e];
    } else {
        int i = (b - eBlocks) * 256 + threadIdx.x;
        if (i < N) {
            if (flag1[i]) wl1[wp1[i] + bsums[512 + (i >> 8)]] = i;
            if (flag2[i]) wl2[wp2[i] + bsums[1024 + (i >> 8)]] = i;
        }
    }
}

// ---------------- MFMA GEMM body: LDS-staged Wt + fused attention scalars ----
__device__ __forceinline__ void gemm_body(
    const unsigned short* __restrict__ Ab, const unsigned short* __restrict__ Wt,
    unsigned short* __restrict__ Bb, float4* __restrict__ asadv,
    const float* __restrict__ asF, const float* __restrict__ adF, int N,
    const int* __restrict__ wl, const int* __restrict__ nactp, int bb) {
    __shared__ __align__(16) unsigned short Ws[128 * 136];
    __shared__ __align__(16) unsigned short Cs[64 * 136];

    int t = threadIdx.x;
    int r0 = bb * 64;
    int nact = wl ? *nactp : N;
    if (r0 >= nact) return;  // uniform per block

    {
        const uint4* src = (const uint4*)Wt;  // 2048 uint4
#pragma unroll
        for (int k = 0; k < 8; k++) {
            int j = t + k * 256;
            int row = j >> 4, c16 = j & 15;
            *(uint4*)&Ws[row * 136 + c16 * 8] = src[j];
        }
    }
    __syncthreads();

    int lane = t & 63;
    int w = t >> 6;
    int ln = lane & 15;
    int quad = lane >> 4;

    int idx = r0 + w * 16 + ln;
    bool valid = idx < nact;
    int arow = idx < N ? idx : N - 1;
    if (wl) arow = valid ? wl[idx] : 0;
    bool wave_active = __any((int)valid);

    if (wave_active) {
        const unsigned short* ap = Ab + (size_t)arow * 128 + quad * 8;

        short8 afrag[4];
        if (valid) {
#pragma unroll
            for (int kt = 0; kt < 4; kt++)
                afrag[kt] = *(const short8*)(ap + kt * 32);
        } else {
#pragma unroll
            for (int kt = 0; kt < 4; kt++)
                afrag[kt] = (short8){0, 0, 0, 0, 0, 0, 0, 0};
        }

        floatx4 acc[8];
#pragma unroll
        for (int nt = 0; nt < 8; nt++) acc[nt] = (floatx4){0.f, 0.f, 0.f, 0.f};

#pragma unroll
        for (int nt = 0; nt < 8; nt++) {
            const unsigned short* wp = Ws + (nt * 16 + ln) * 136 + quad * 8;
#pragma unroll
            for (int kt = 0; kt < 4; kt++) {
                short8 bfrag = *(const short8*)(wp + kt * 32);
                acc[nt] = MF(afrag[kt], bfrag, acc[nt]);
            }
        }

        float as0[4] = {0, 0, 0, 0}, as1[4] = {0, 0, 0, 0};
        float ad0[4] = {0, 0, 0, 0}, ad1[4] = {0, 0, 0, 0};
#pragma unroll
        for (int nt = 0; nt < 8; nt++) {
            float asc = asF[nt * 16 + ln];
            float adc = adF[nt * 16 + ln];
#pragma unroll
            for (int r = 0; r < 4; r++) {
                float v = acc[nt][r];
                Cs[(w * 16 + quad * 4 + r) * 136 + nt * 16 + ln] = f2us(v);
                if (nt < 4) { as0[r] += v * asc; ad0[r] += v * adc; }
                else        { as1[r] += v * asc; ad1[r] += v * adc; }
            }
        }
#pragma unroll
        for (int mask = 1; mask <= 8; mask <<= 1) {
#pragma unroll
            for (int r = 0; r < 4; r++) {
                as0[r] += __shfl_xor(as0[r], mask);
                as1[r] += __shfl_xor(as1[r], mask);
                ad0[r] += __shfl_xor(ad0[r], mask);
                ad1[r] += __shfl_xor(ad1[r], mask);
            }
        }
        if (ln == 0) {
#pragma unroll
            for (int r = 0; r < 4; r++) {
                int idx3 = r0 + w * 16 + quad * 4 + r;
                if (idx3 < nact) {
                    int row = wl ? wl[idx3] : idx3;
                    asadv[row] = make_float4(as0[r], as1[r], ad0[r], ad1[r]);
                }
            }
        }
    }
    __syncthreads();

    {
        int idx2 = r0 + (t >> 2);
        int cseg = (t & 3) * 32;
        if (idx2 < nact) {
            int grow = wl ? wl[idx2] : idx2;
            const short8* srcp = (const short8*)&Cs[(t >> 2) * 136 + cseg];
            short8* dstp = (short8*)&Bb[(size_t)grow * 128 + cseg];
#pragma unroll
            for (int u = 0; u < 4; u++) dstp[u] = srcp[u];
        }
    }
}

__global__ __launch_bounds__(256) void k_gemm_mfma(
    const unsigned short* __restrict__ Ab, const unsigned short* __restrict__ Wt,
    unsigned short* __restrict__ Bb, float4* __restrict__ asadv,
    const float* __restrict__ asF, const float* __restrict__ adF, int N,
    const int* __restrict__ wl, const int* __restrict__ nactp) {
    gemm_body(Ab, Wt, Bb, asadv, asF, adF, N, wl, nactp, blockIdx.x);
}

// layer 0: full GEMM fused with the (atomic-free) mark2 edge scan
__global__ __launch_bounds__(256) void k_gemm0_mark(
    const unsigned short* __restrict__ Ab, const unsigned short* __restrict__ Wt,
    unsigned short* __restrict__ Bb, float4* __restrict__ asadv,
    const float* __restrict__ asF, const float* __restrict__ adF, int N,
    const int* __restrict__ ei, const unsigned char* __restrict__ rootb,
    unsigned char* __restrict__ flag2, int E, int markBlocks) {
    int b = blockIdx.x;
    if (b < markBlocks) {
        int e = b * 256 + threadIdx.x;
        if (e < E) {
            int d = ei[E + e];
            if (rootb[d]) flag2[ei[e]] = 1;
        }
        return;
    }
    gemm_body(Ab, Wt, Bb, asadv, asF, adF, N, nullptr, nullptr, b - markBlocks);
}

// ---------------- GAT aggregation over a compact worklist ----------------
// byidx: write output row = worklist index (compact, for root aggregation)
// nfix: host-known node count (overrides *nactp)
__global__ void k_gat_agg(const uint2* __restrict__ Bu2, const float4* __restrict__ asadv,
                          const int* __restrict__ offs, const int* __restrict__ bsums,
                          const int* __restrict__ counts,
                          const int* __restrict__ adj, const float* __restrict__ biasF,
                          uint2* __restrict__ Au2, float2* __restrict__ pE,
                          const int* __restrict__ nactp, int nfix, int dorelu, int byidx,
                          const int* __restrict__ wl) {
    int wave = (blockIdx.x * blockDim.x + threadIdx.x) >> 6;
    int lane = threadIdx.x & 63;
    int hl = lane & 31;          // lane within node-half
    int hb = lane & 32;          // shfl broadcast base for this half
    int idx = wave * 2 + (lane >> 5);
    int n = nfix ? nfix : *nactp;
    if (idx >= n) return;        // half-wave exits; shfls stay in-half
    int node = wl[idx];
    int head = hl >> 4;

    float4 self = asadv[node];
    float ad0 = self.z, ad1 = self.w;
    float es0 = __expf(leaky(self.x + ad0));
    float es1 = __expf(leaky(self.y + ad1));

    int o = offs[node] + bsums[node >> 8];
    int c = counts[node];
    uint2 hvs = Bu2[(size_t)node * 32 + hl];
    float acc0, acc1, acc2, acc3;

    if (c <= 32) {
        // ---- fast path ----
        int src_r = 0;
        float p0 = 0.f, p1 = 0.f;
        if (hl < c) {
            src_r = adj[o + hl];
            float4 av = asadv[src_r];
            p0 = __expf(leaky(av.x + ad0));
            p1 = __expf(leaky(av.y + ad1));
        }
        float t0 = p0, t1 = p1;
#pragma unroll
        for (int mask = 1; mask <= 16; mask <<= 1) {
            t0 += __shfl_xor(t0, mask);
            t1 += __shfl_xor(t1, mask);
        }
        float inv0 = 1.f / (es0 + t0 + 1e-16f);
        float inv1 = 1.f / (es1 + t1 + 1e-16f);
        p0 *= inv0;
        p1 *= inv1;
        float aself = head ? es1 * inv1 : es0 * inv0;
        acc0 = aself * lo2f(hvs.x);
        acc1 = aself * hi2f(hvs.x);
        acc2 = aself * lo2f(hvs.y);
        acc3 = aself * hi2f(hvs.y);

        uint2 hq[4];
#pragma unroll
        for (int j = 0; j < 4; j++) {
            int s2 = __shfl(src_r, hb + j);
            hq[j] = make_uint2(0u, 0u);
            if (j < c) hq[j] = Bu2[(size_t)s2 * 32 + hl];
        }

        for (int base = 0; base < c; base += 4) {
            uint2 cu[4];
            float av4[4];
#pragma unroll
            for (int j = 0; j < 4; j++) {
                cu[j] = hq[j];
                int idx2 = (base + j) & 31;
                float a0 = __shfl(p0, hb + idx2);   // full-exec broadcasts
                float a1 = __shfl(p1, hb + idx2);
                float a = head ? a1 : a0;
                av4[j] = (base + j < c) ? a : 0.f;
            }
#pragma unroll
            for (int j = 0; j < 4; j++) {
                int nx = base + 4 + j;
                int s2 = __shfl(src_r, hb + (nx & 31));
                if (nx < c) hq[j] = Bu2[(size_t)s2 * 32 + hl];
            }
#pragma unroll
            for (int j = 0; j < 4; j++) {
                acc0 += av4[j] * lo2f(cu[j].x);
                acc1 += av4[j] * hi2f(cu[j].x);
                acc2 += av4[j] * lo2f(cu[j].y);
                acc3 += av4[j] * hi2f(cu[j].y);
            }
        }
    } else {
        // ---- slow path (rare, c>32) ----
        float sum0 = es0, sum1 = es1;
        for (int base = 0; base < c; base += 32) {
            int i = base + hl;
            float p0 = 0.f, p1 = 0.f;
            if (i < c) {
                int s = adj[o + i];
                float4 av = asadv[s];
                p0 = __expf(leaky(av.x + ad0));
                p1 = __expf(leaky(av.y + ad1));
                pE[o + i] = make_float2(p0, p1);
            }
            float t0 = p0, t1 = p1;
#pragma unroll
            for (int mask = 1; mask <= 16; mask <<= 1) {
                t0 += __shfl_xor(t0, mask);
                t1 += __shfl_xor(t1, mask);
            }
            sum0 += t0; sum1 += t1;
        }
        float inv0 = 1.f / (sum0 + 1e-16f);
        float inv1 = 1.f / (sum1 + 1e-16f);
        float aself = head ? es1 * inv1 : es0 * inv0;
        float invh = head ? inv1 : inv0;
        acc0 = aself * lo2f(hvs.x);
        acc1 = aself * hi2f(hvs.x);
        acc2 = aself * lo2f(hvs.y);
        acc3 = aself * hi2f(hvs.y);
        for (int i = 0; i < c; i++) {
            int s = adj[o + i];
            float2 pp = pE[o + i];
            uint2 hv = Bu2[(size_t)s * 32 + hl];
            float a = (head ? pp.y : pp.x) * invh;
            acc0 += a * lo2f(hv.x);
            acc1 += a * hi2f(hv.x);
            acc2 += a * lo2f(hv.y);
            acc3 += a * hi2f(hv.y);
        }
    }

    float4 bb4 = ((const float4*)biasF)[hl];
    float q0 = acc0 + bb4.x;
    float q1 = acc1 + bb4.y;
    float q2 = acc2 + bb4.z;
    float q3 = acc3 + bb4.w;
    if (dorelu) {
        q0 = fmaxf(q0, 0.f); q1 = fmaxf(q1, 0.f);
        q2 = fmaxf(q2, 0.f); q3 = fmaxf(q3, 0.f);
    }
    Au2[(size_t)(byidx ? idx : node) * 32 + hl] =
        make_uint2(((unsigned)f2us(q1) << 16) | f2us(q0),
                   ((unsigned)f2us(q3) << 16) | f2us(q2));
}

// ---------------- heads: MFMA-batched over graphs ----------------
// 4 blocks x 4 waves; each wave = 16 graphs = one 16-row MFMA tile.
// Chain: zf -> {ptr x3, cat, sf x2} -> bool -> size, intermediates in a
// per-wave LDS tile T[16][168] (bf16), weights pre-transposed in Whd.
// C-frag layout (verified via gemm_body): row=quad*4+r, col=nt*16+ln.
template <int F32>
__device__ void heads_mfma_body(
    const unsigned* __restrict__ hroot32, const void* __restrict__ x,
    const int* __restrict__ node0, const unsigned short* __restrict__ Whd,
    const void* sb, const void* pb1, const void* pW2, const void* pb2,
    const void* cb1, const void* cW2, const void* cb2,
    const void* fb1, const void* fW2, const void* fb2,
    const void* bb1, const void* bW2, const void* bb2,
    const void* zb1, const void* zW2, const void* zb2,
    void* __restrict__ outv) {
    __shared__ __align__(16) unsigned short hinS[64 * 168];
    __shared__ __align__(16) unsigned short TwS[4][16 * 168];

    int t = threadIdx.x;
    int g0b = blockIdx.x * 64;
    bf16* outb = (bf16*)outv;
    float* outf = (float*)outv;
#define STORE(idx, val) do { if (F32) outf[idx] = (val); else outb[idx] = __float2bfloat16(val); } while (0)

    // ---- prologue: hinS[64][168] = [hroot(128) | dtype(22) | 0-pad(18)] ----
    {
        unsigned* h32 = (unsigned*)hinS;
        for (int j = t; j < 64 * 64; j += 256) {
            int gl = j >> 6, c = j & 63;
            h32[gl * 84 + c] = hroot32[(size_t)(g0b + gl) * 64 + c];
        }
        for (int j = t; j < 64 * 20; j += 256) {
            int gl = j / 20, c = j - gl * 20;
            int n0 = node0[g0b + gl];
            int k0 = 2 * c;
            float d0 = (k0 < 22) ? LDWt<F32>(x, (size_t)n0 * 128 + k0) : 0.f;
            float d1 = (k0 + 1 < 22) ? LDWt<F32>(x, (size_t)n0 * 128 + k0 + 1) : 0.f;
            h32[gl * 84 + 64 + c] = ((unsigned)f2us(d1) << 16) | f2us(d0);
        }
    }
    __syncthreads();

    int w = t >> 6;
    int lane = t & 63;
    int ln = lane & 15, quad = lane >> 4;
    unsigned short* T = TwS[w];
    int gq = quad * 4;               // local graph base for this lane's C rows
    int gw0 = g0b + w * 16;          // global graph base for the wave

    // bin cols 64..95: dtype(22) then zeros (cat/sf/bool filled later)
    for (int j = lane; j < 16 * 32; j += 64) {
        int gl = j >> 5, c = j & 31;
        T[gl * 168 + 64 + c] =
            (c < 22) ? hinS[(w * 16 + gl) * 168 + 128 + c] : (unsigned short)0;
    }

    // ---- stage zf: [16x160] @ sWt[160x64], relu ----
    short8 afA[5];
#pragma unroll
    for (int kt = 0; kt < 5; kt++)
        afA[kt] = *(const short8*)&hinS[(w * 16 + ln) * 168 + quad * 8 + kt * 32];
#pragma unroll
    for (int nt = 0; nt < 4; nt++) {
        floatx4 acc = (floatx4){0.f, 0.f, 0.f, 0.f};
        const unsigned short* bp = Whd + (nt * 16 + ln) * 160 + quad * 8;
#pragma unroll
        for (int kt = 0; kt < 5; kt++)
            acc = MF(afA[kt], *(const short8*)(bp + kt * 32), acc);
        float bias = LDWt<F32>(sb, nt * 16 + ln);
#pragma unroll
        for (int r = 0; r < 4; r++)
            T[(gq + r) * 168 + nt * 16 + ln] = f2us(fmaxf(acc[r] + bias, 0.f));
    }
    __syncthreads();

    short8 af20 = *(const short8*)&T[ln * 168 + quad * 8];
    short8 af21 = *(const short8*)&T[ln * 168 + quad * 8 + 32];

    // ---- ptr heads k=0..2 ----
#pragma unroll
    for (int k = 0; k < 3; k++) {
        const unsigned short* Bw = Whd + 10240 + k * 4096;
        floatx4 acc[4];
#pragma unroll
        for (int nt = 0; nt < 4; nt++) {
            floatx4 a = (floatx4){0.f, 0.f, 0.f, 0.f};
            const unsigned short* bp = Bw + (nt * 16 + ln) * 64 + quad * 8;
            a = MF(af20, *(const short8*)bp, a);
            a = MF(af21, *(const short8*)(bp + 32), a);
            float b1 = LDWt<F32>(pb1, k * 64 + nt * 16 + ln);
#pragma unroll
            for (int r = 0; r < 4; r++) a[r] = fmaxf(a[r] + b1, 0.f);
            acc[nt] = a;
        }
#pragma unroll
        for (int o = 0; o < 3; o++) {
            float w2[4], part[4];
#pragma unroll
            for (int nt = 0; nt < 4; nt++)
                w2[nt] = LDWt<F32>(pW2, (size_t)k * 192 + (size_t)(nt * 16 + ln) * 3 + o);
#pragma unroll
            for (int r = 0; r < 4; r++)
                part[r] = acc[0][r] * w2[0] + acc[1][r] * w2[1] +
                          acc[2][r] * w2[2] + acc[3][r] * w2[3];
            quadred(part);
            if (ln == 0) {
                float b2 = LDWt<F32>(pb2, k * 3 + o);
#pragma unroll
                for (int r = 0; r < 4; r++)
                    STORE(k * 768 + (gw0 + gq + r) * 3 + o, part[r] + b2);
            }
        }
    }

    // ---- cat head (outs -> T cols 86..90) ----
    {
        const unsigned short* Bw = Whd + 22528;
        floatx4 acc[4];
#pragma unroll
        for (int nt = 0; nt < 4; nt++) {
            floatx4 a = (floatx4){0.f, 0.f, 0.f, 0.f};
            const unsigned short* bp = Bw + (nt * 16 + ln) * 64 + quad * 8;
            a = MF(af20, *(const short8*)bp, a);
            a = MF(af21, *(const short8*)(bp + 32), a);
            float b1 = LDWt<F32>(cb1, nt * 16 + ln);
#pragma unroll
            for (int r = 0; r < 4; r++) a[r] = fmaxf(a[r] + b1, 0.f);
            acc[nt] = a;
        }
#pragma unroll
        for (int o = 0; o < 5; o++) {
            float w2[4], part[4];
#pragma unroll
            for (int nt = 0; nt < 4; nt++)
                w2[nt] = LDWt<F32>(cW2, (size_t)(nt * 16 + ln) * 5 + o);
#pragma unroll
            for (int r = 0; r < 4; r++)
                part[r] = acc[0][r] * w2[0] + acc[1][r] * w2[1] +
                          acc[2][r] * w2[2] + acc[3][r] * w2[3];
            quadred(part);
            if (ln == 0) {
                float b2 = LDWt<F32>(cb2, o);
#pragma unroll
                for (int r = 0; r < 4; r++) {
                    float v = part[r] + b2;
                    T[(gq + r) * 168 + 86 + o] = f2us(v);
                    STORE(2304 + (gw0 + gq + r) * 5 + o, v);
                }
            }
        }
    }

    // ---- sf heads k=0,1 (outs -> T cols 91,92) ----
#pragma unroll
    for (int k = 0; k < 2; k++) {
        const unsigned short* Bw = Whd + 26624 + k * 4096;
        floatx4 acc[4];
#pragma unroll
        for (int nt = 0; nt < 4; nt++) {
            floatx4 a = (floatx4){0.f, 0.f, 0.f, 0.f};
            const unsigned short* bp = Bw + (nt * 16 + ln) * 64 + quad * 8;
            a = MF(af20, *(const short8*)bp, a);
            a = MF(af21, *(const short8*)(bp + 32), a);
            float b1 = LDWt<F32>(fb1, k * 64 + nt * 16 + ln);
#pragma unroll
            for (int r = 0; r < 4; r++) a[r] = fmaxf(a[r] + b1, 0.f);
            acc[nt] = a;
        }
        float w2[4], part[4];
#pragma unroll
        for (int nt = 0; nt < 4; nt++)
            w2[nt] = LDWt<F32>(fW2, (size_t)k * 64 + nt * 16 + ln);
#pragma unroll
        for (int r = 0; r < 4; r++)
            part[r] = acc[0][r] * w2[0] + acc[1][r] * w2[1] +
                      acc[2][r] * w2[2] + acc[3][r] * w2[3];
        quadred(part);
        if (ln == 0) {
            float b2 = LDWt<F32>(fb2, k);
#pragma unroll
            for (int r = 0; r < 4; r++) {
                float v = part[r] + b2;
                T[(gq + r) * 168 + 91 + k] = f2us(v);
                STORE(3584 + k * 256 + (gw0 + gq + r), v);
            }
        }
    }
    __syncthreads();

    short8 af3 = *(const short8*)&T[ln * 168 + 64 + quad * 8];

    // ---- bool head: K=96 = [zf(64) | dtype/cat/sf(29) | 0] ----
    {
        const unsigned short* Bw = Whd + 34816;  // bW1t[64][96], rows 93..95 = 0
        floatx4 acc[4];
#pragma unroll
        for (int nt = 0; nt < 4; nt++) {
            floatx4 a = (floatx4){0.f, 0.f, 0.f, 0.f};
            const unsigned short* bp = Bw + (nt * 16 + ln) * 96 + quad * 8;
            a = MF(af20, *(const short8*)bp, a);
            a = MF(af21, *(const short8*)(bp + 32), a);
            a = MF(af3, *(const short8*)(bp + 64), a);
            float b1 = LDWt<F32>(bb1, nt * 16 + ln);
#pragma unroll
            for (int r = 0; r < 4; r++) a[r] = fmaxf(a[r] + b1, 0.f);
            acc[nt] = a;
        }
        float w2[4], part[4];
#pragma unroll
        for (int nt = 0; nt < 4; nt++)
            w2[nt] = LDWt<F32>(bW2, nt * 16 + ln);
#pragma unroll
        for (int r = 0; r < 4; r++)
            part[r] = acc[0][r] * w2[0] + acc[1][r] * w2[1] +
                      acc[2][r] * w2[2] + acc[3][r] * w2[3];
        quadred(part);
        if (ln == 0) {
            float b2 = LDWt<F32>(bb2, 0);
#pragma unroll
            for (int r = 0; r < 4; r++) {
                float v = part[r] + b2;
                T[(gq + r) * 168 + 93] = f2us(v);  // col 93 <- bool logit
                STORE(4096 + (gw0 + gq + r), v);
            }
        }
    }
    __syncthreads();

    af3 = *(const short8*)&T[ln * 168 + 64 + quad * 8];  // col 93 updated

    // ---- size head: K=96 (zW1t rows 94,95 = 0) ----
    {
        const unsigned short* Bw = Whd + 40960;
        floatx4 acc[4];
#pragma unroll
        for (int nt = 0; nt < 4; nt++) {
            floatx4 a = (floatx4){0.f, 0.f, 0.f, 0.f};
            const unsigned short* bp = Bw + (nt * 16 + ln) * 96 + quad * 8;
            a = MF(af20, *(const short8*)bp, a);
            a = MF(af21, *(const short8*)(bp + 32), a);
            a = MF(af3, *(const short8*)(bp + 64), a);
            float b1 = LDWt<F32>(zb1, nt * 16 + ln);
#pragma unroll
            for (int r = 0; r < 4; r++) a[r] = fmaxf(a[r] + b1, 0.f);
            acc[nt] = a;
        }
#pragma unroll
        for (int o = 0; o < 8; o++) {
            float w2[4], part[4];
#pragma unroll
            for (int nt = 0; nt < 4; nt++)
                w2[nt] = LDWt<F32>(zW2, (size_t)(nt * 16 + ln) * 8 + o);
#pragma unroll
            for (int r = 0; r < 4; r++)
                part[r] = acc[0][r] * w2[0] + acc[1][r] * w2[1] +
                          acc[2][r] * w2[2] + acc[3][r] * w2[3];
            quadred(part);
            if (ln == 0) {
                float b2 = LDWt<F32>(zb2, o);
#pragma unroll
                for (int r = 0; r < 4; r++)
                    STORE(4352 + (gw0 + gq + r) * 8 + o, part[r] + b2);
            }
        }
    }
#undef STORE
}

__global__ __launch_bounds__(256) void k_heads_mfma(
    const unsigned* __restrict__ hroot32, const void* __restrict__ x,
    const int* __restrict__ node0, const unsigned short* __restrict__ Whd,
    const void* sb, const void* pb1, const void* pW2, const void* pb2,
    const void* cb1, const void* cW2, const void* cb2,
    const void* fb1, const void* fW2, const void* fb2,
    const void* bb1, const void* bW2, const void* bb2,
    const void* zb1, const void* zW2, const void* zb2,
    void* __restrict__ outv, const int* __restrict__ flagv) {
    if (or16(flagv))
        heads_mfma_body<1>(hroot32, x, node0, Whd, sb, pb1, pW2, pb2, cb1, cW2, cb2,
                           fb1, fW2, fb2, bb1, bW2, bb2, zb1, zW2, zb2, outv);
    else
        heads_mfma_body<0>(hroot32, x, node0, Whd, sb, pb1, pW2, pb2, cb1, cW2, cb2,
                           fb1, fW2, fb2, bb1, bW2, bb2, zb1, zW2, zb2, outv);
}

// ---------------- host ----------------

extern "C" void kernel_launch(void* const* d_in, const int* in_sizes, int n_in,
                              void* d_out, int out_size, void* d_ws, size_t ws_size,
                              hipStream_t stream) {
    const void* x     = d_in[0];
    const int*  ei    = (const int*)d_in[1];
    const int*  batch = (const int*)d_in[2];

    int N = in_sizes[0] / 128;
    int E = in_sizes[1] / 2;

    char* w = (char*)d_ws;
    float4* asad = (float4*)w;              w += (size_t)N * 16;
    unsigned short* A = (unsigned short*)w; w += (size_t)N * 128 * 2;
    unsigned short* B = (unsigned short*)w; w += (size_t)N * 128 * 2;
    float2* pE = (float2*)w;                w += (size_t)E * 8;
    unsigned short* Wt = (unsigned short*)w; w += 3 * 16384 * 2;
    unsigned short* Whd = (unsigned short*)w; w += 47104 * 2;
    float* asF = (float*)w;                 w += 384 * 4;
    float* adF = (float*)w;                 w += 384 * 4;
    float* bF = (float*)w;                  w += 384 * 4;
    int* offs = (int*)w;                    w += (size_t)N * 4;
    int* wp1 = (int*)w;                     w += (size_t)N * 4;
    int* wp2 = (int*)w;                     w += (size_t)N * 4;
    int* wl1 = (int*)w;                     w += (size_t)N * 4;
    int* wl2 = (int*)w;                     w += (size_t)N * 4;
    int* adj = (int*)w;                     w += (size_t)E * 4;
    int* bsums = (int*)w;                   w += 3 * 512 * 4;
    int* node0 = (int*)w;                   w += 256 * 4;
    int* nact = (int*)w;                    w += 64;
    unsigned* hroot = (unsigned*)w;         w += 256 * 128 * 2;
    // ---- contiguous zero-region (zeroed by k_detect_zero) ----
    char* zbase = w;
    int* counts = (int*)w;                  w += (size_t)N * 4;
    int* cur = (int*)w;                     w += (size_t)N * 4;
    unsigned char* flag1 = (unsigned char*)w; w += (size_t)N;
    unsigned char* flag2 = (unsigned char*)w; w += (size_t)N;
    unsigned char* rootb = (unsigned char*)w; w += (size_t)N;
    size_t zbytes = (size_t)N * 11;
    int* flagv = (int*)w;                   w += 64;

    int nb = (N + 255) / 256;
    int nvec = N * 16;
    int nbx8 = (nvec + 255) / 256;
    int nbE = (E + 255) / 256;
    int gemmBlocks = (N + 63) / 64;
    int zBlocks = (int)((zbytes + 4095) / 4096);

    k_detect_zero<<<16 + zBlocks, 256, 0, stream>>>(x, flagv, zbase, zbytes);

    k_prep_fused<<<nbx8 + 194 + 184 + nb, 256, 0, stream>>>(
        x, A, nvec, d_in[3], Wt, d_in[4], d_in[5], d_in[6],
        asF, adF, bF,
        d_in[7], d_in[9], d_in[13], d_in[17], d_in[21], d_in[25], Whd,
        batch, node0, rootb, flag2, N, flagv, nbx8);

    // layer-0 GEMM (LDS-staged Wt) fused with the mark2 edge scan
    k_gemm0_mark<<<nbE + gemmBlocks, 256, 0, stream>>>(
        A, Wt, B, asad, asF, adF, N, ei, rootb, flag2, E, nbE);

    // flag1 = flag2 ∪ srcs(flag2)
    k_mark1<<<nbE + nb, 256, 0, stream>>>(ei, flag2, flag1, E, N, nbE);

    // histogram: non-returning atomics only for flag1 dsts
    k_hist_masked<<<nbE, 256, 0, stream>>>(ei, flag1, counts, E);

    // triple scan: counts -> offs, flag1 -> wp1, flag2 -> wp2
    k_scan3x<<<nb, 256, 0, stream>>>(counts, flag1, flag2, offs, wp1, wp2, bsums, N);
    k_scan2x<<<1, 512, 0, stream>>>(bsums, nb, nact);

    // single-pass cursor scatter + worklists (ei fetched once, not 8x)
    k_scatter_wl<<<nbE + nb, 256, 0, stream>>>(
        ei, offs, bsums, cur, flag1, flag2, wp1, wp2, adj, wl1, wl2, E, N, nbE);

    int nwaves = (N + 1) / 2;
    int aggblocks = (nwaves + 3) / 4;

    // layer 0 agg over wl1
    k_gat_agg<<<aggblocks, 256, 0, stream>>>(
        (const uint2*)B, asad, offs, bsums, counts, adj, bF, (uint2*)A, pE,
        nact, 0, 1, 0, wl1);

    // layer 1: gather-GEMM over wl1, agg over wl2
    k_gemm_mfma<<<gemmBlocks, 256, 0, stream>>>(
        A, Wt + 16384, B, asad, asF + 128, adF + 128, N, wl1, nact);
    k_gat_agg<<<aggblocks, 256, 0, stream>>>(
        (const uint2*)B, asad, offs, bsums, counts, adj, bF + 128, (uint2*)A, pE,
        nact + 1, 0, 1, 0, wl2);

    // layer 2: gather-GEMM over wl2
    k_gemm_mfma<<<gemmBlocks, 256, 0, stream>>>(
        A, Wt + 2 * 16384, B, asad, asF + 256, adF + 256, N, wl2, nact + 1);

    // root aggregation (256 roots, compact output, no relu, layer-2 bias)
    k_gat_agg<<<32, 256, 0, stream>>>(
        (const uint2*)B, asad, offs, bsums, counts, adj, bF + 256, (uint2*)hroot, pE,
        nact, 256, 0, 1, node0);

    // MFMA-batched heads
    k_heads_mfma<<<4, 256, 0, stream>>>(
        hroot, x, node0, Whd,
        d_in[8], d_in[10], d_in[11], d_in[12],
        d_in[14], d_in[15], d_in[16],
        d_in[18], d_in[19], d_in[20],
        d_in[22], d_in[23], d_in[24],
        d_in[26], d_in[27], d_in[28],
        d_out, flagv);
}